// Round 9
// baseline (191.846 us; speedup 1.0000x reference)
//
#include <hip/hip_runtime.h>
#include <hip/hip_bf16.h>
#include <math.h>

typedef __attribute__((ext_vector_type(8))) short bf16x8;
typedef __attribute__((ext_vector_type(8))) unsigned short u16x8;
typedef __attribute__((ext_vector_type(4))) float f32x4;

__device__ __forceinline__ unsigned short f2bf(float f) {
  union { float f; unsigned u; } c; c.f = f;
  unsigned u = c.u;
  u += 0x7fffu + ((u >> 16) & 1u);   // round-to-nearest-even
  return (unsigned short)(u >> 16);
}
__device__ __forceinline__ unsigned fb(float x) {
  union { float f; unsigned u; } c; c.f = x; return c.u;
}
// async global->LDS, 16B per lane; LDS dest must be wave-uniform base + lane*16
__device__ __forceinline__ void async16(const unsigned short* g, unsigned short* l) {
  __builtin_amdgcn_global_load_lds(
      (const __attribute__((address_space(1))) unsigned int*)g,
      (__attribute__((address_space(3))) unsigned int*)l, 16, 0, 0);
}

// -------- fused prep: z<4 transpose+cast weights (z=0 Wq scaled by C); z=4 cast x --------
__global__ __launch_bounds__(256) void prep_kernel(
    const float* __restrict__ x, const float* __restrict__ Wq,
    const float* __restrict__ Wk, const float* __restrict__ Wv,
    const float* __restrict__ Wo, unsigned short* __restrict__ Xb,
    unsigned short* __restrict__ Wqkvt, unsigned short* __restrict__ Wot) {
  const int z = blockIdx.z;
  if (z == 4) {  // cast x: 1M float4 over 1024 blocks, 4 float4/thread
    const int bid = blockIdx.y * 32 + blockIdx.x;
#pragma unroll
    for (int i = 0; i < 4; ++i) {
      const int idx = (bid * 4 + i) * 256 + threadIdx.x;
      float4 v = ((const float4*)x)[idx];
      ushort4 o;
      o.x = f2bf(v.x); o.y = f2bf(v.y); o.z = f2bf(v.z); o.w = f2bf(v.w);
      ((ushort4*)Xb)[idx] = o;
    }
    return;
  }
  __shared__ float t[32][33];
  const float* src = (z == 0) ? Wq : (z == 1) ? Wk : (z == 2) ? Wv : Wo;
  unsigned short* dst = (z < 3) ? (Wqkvt + (size_t)z * 1024 * 1024) : Wot;
  const float scale = (z == 0) ? 0.18033688f : 1.0f;  // log2(e)/sqrt(64) into Wq
  int tx = threadIdx.x & 31, ty = threadIdx.x >> 5;
  int bx = blockIdx.x, by = blockIdx.y;
#pragma unroll
  for (int i = 0; i < 4; ++i)
    t[ty + i * 8][tx] = src[(size_t)(by * 32 + ty + i * 8) * 1024 + bx * 32 + tx];
  __syncthreads();
#pragma unroll
  for (int i = 0; i < 4; ++i)
    dst[(size_t)(bx * 32 + ty + i * 8) * 1024 + by * 32 + tx] = f2bf(t[tx][ty + i * 8] * scale);
}

// ---------------- QKV GEMM: 128x128 tile, BK=64, XCD-swizzled ----------------
// (epilogue = exact R11 form; Q-scale lives in the weights now)
__global__ __launch_bounds__(256) void gemm_qkv(
    const unsigned short* __restrict__ A, const unsigned short* __restrict__ Bt,
    unsigned short* __restrict__ Qh, unsigned short* __restrict__ Kh,
    unsigned short* __restrict__ Vt, int K) {
  __shared__ unsigned short As [128][32];  // unpadded: global_load_lds lane ordering
  __shared__ unsigned short As2[128][32];
  __shared__ unsigned short Bs [128][32];
  __shared__ unsigned short Bs2[128][32];
  const int flat = blockIdx.x;
  const int xcd = flat & 7, idx = flat >> 3;      // 96 blocks per XCD
  const int mg = xcd >> 1, ng = xcd & 1;          // 4x2 XCD rectangle grid
  const int m0 = (mg * 8 + (idx & 7)) * 128;      // 32 m-tiles
  const int n0 = (ng * 12 + (idx >> 3)) * 128;    // 24 n-tiles
  const int tid = threadIdx.x;
  const int wave = tid >> 6, lane = tid & 63;
  const int quad = lane >> 4, l16 = lane & 15;
  const int wm = (wave >> 1) * 64, wn = (wave & 1) * 64;
  const int srow = tid >> 2, sch = (tid & 3) * 8;  // LDS byte addr = tid*16
  f32x4 acc[4][4] = {};

  for (int k0 = 0; k0 < K; k0 += 64) {
    __syncthreads();
    async16(A  + (size_t)(m0 + srow) * K + k0 + sch,           &As [srow][sch]);
    async16(A  + (size_t)(m0 + srow + 64) * K + k0 + sch,      &As [srow + 64][sch]);
    async16(A  + (size_t)(m0 + srow) * K + k0 + 32 + sch,      &As2[srow][sch]);
    async16(A  + (size_t)(m0 + srow + 64) * K + k0 + 32 + sch, &As2[srow + 64][sch]);
    async16(Bt + (size_t)(n0 + srow) * K + k0 + sch,           &Bs [srow][sch]);
    async16(Bt + (size_t)(n0 + srow + 64) * K + k0 + sch,      &Bs [srow + 64][sch]);
    async16(Bt + (size_t)(n0 + srow) * K + k0 + 32 + sch,      &Bs2[srow][sch]);
    async16(Bt + (size_t)(n0 + srow + 64) * K + k0 + 32 + sch, &Bs2[srow + 64][sch]);
    __syncthreads();
    bf16x8 af[4], bfr[4];
#pragma unroll
    for (int i = 0; i < 4; ++i) {
      af[i]  = *(const bf16x8*)&As[wm + i * 16 + l16][quad * 8];
      bfr[i] = *(const bf16x8*)&Bs[wn + i * 16 + l16][quad * 8];
    }
#pragma unroll
    for (int mi = 0; mi < 4; ++mi)
#pragma unroll
      for (int ni = 0; ni < 4; ++ni)
        acc[mi][ni] = __builtin_amdgcn_mfma_f32_16x16x32_bf16(af[mi], bfr[ni], acc[mi][ni], 0, 0, 0);
#pragma unroll
    for (int i = 0; i < 4; ++i) {
      af[i]  = *(const bf16x8*)&As2[wm + i * 16 + l16][quad * 8];
      bfr[i] = *(const bf16x8*)&Bs2[wn + i * 16 + l16][quad * 8];
    }
#pragma unroll
    for (int mi = 0; mi < 4; ++mi)
#pragma unroll
      for (int ni = 0; ni < 4; ++ni)
        acc[mi][ni] = __builtin_amdgcn_mfma_f32_16x16x32_bf16(af[mi], bfr[ni], acc[mi][ni], 0, 0, 0);
  }

#pragma unroll
  for (int mi = 0; mi < 4; ++mi) {
#pragma unroll
    for (int ni = 0; ni < 4; ++ni) {
      const int col = n0 + wn + ni * 16 + l16;
      const int token0 = m0 + wm + mi * 16 + quad * 4;
      const int bb = token0 >> 11, s0 = token0 & 2047;
      if (col < 2048) {  // Q or K, head-major [bh][s][64]
        const int hh = (col & 1023) >> 6, d = col & 63;
        unsigned short* dst = (col < 1024) ? Qh : Kh;
        dst += ((size_t)(bb * 16 + hh) * 2048 + s0) * 64 + d;
#pragma unroll
        for (int r = 0; r < 4; ++r) dst[(size_t)r * 64] = f2bf(acc[mi][ni][r]);
      } else {           // V, tiled [bh][s>>5][d][32]
        const int vc = col - 2048, hh = vc >> 6, d = vc & 63;
        ushort4 us;
        us.x = f2bf(acc[mi][ni][0]); us.y = f2bf(acc[mi][ni][1]);
        us.z = f2bf(acc[mi][ni][2]); us.w = f2bf(acc[mi][ni][3]);
        *(ushort4*)&Vt[(((size_t)(bb * 16 + hh) * 64 + (s0 >> 5)) * 64 + d) * 32 + (s0 & 31)] = us;
      }
    }
  }
}

// ---------------- output GEMM: 128x64 tile, BK=64, XCD-swizzled ----------------
__global__ __launch_bounds__(256) void gemm_out(
    const unsigned short* __restrict__ A, const unsigned short* __restrict__ Bt,
    float* __restrict__ C, const float* __restrict__ bias, int N, int K) {
  __shared__ unsigned short As [128][32];
  __shared__ unsigned short As2[128][32];
  __shared__ unsigned short Bs [64][32];
  __shared__ unsigned short Bs2[64][32];
  const int flat = blockIdx.x;
  const int xcd = flat & 7, idx = flat >> 3;      // 64 blocks per XCD
  const int mg = xcd >> 1, ng = xcd & 1;
  const int m0 = (mg * 8 + (idx & 7)) * 128;      // 32 m-tiles
  const int n0 = (ng * 8 + (idx >> 3)) * 64;      // 16 n-tiles
  const int tid = threadIdx.x;
  const int wave = tid >> 6, lane = tid & 63;
  const int quad = lane >> 4, l16 = lane & 15;
  const int wm = (wave >> 1) * 64, wn = (wave & 1) * 32;
  const int srow = tid >> 2, sch = (tid & 3) * 8;
  f32x4 acc[4][2] = {};

  for (int k0 = 0; k0 < K; k0 += 64) {
    __syncthreads();
    async16(A  + (size_t)(m0 + srow) * K + k0 + sch,           &As [srow][sch]);
    async16(A  + (size_t)(m0 + srow + 64) * K + k0 + sch,      &As [srow + 64][sch]);
    async16(A  + (size_t)(m0 + srow) * K + k0 + 32 + sch,      &As2[srow][sch]);
    async16(A  + (size_t)(m0 + srow + 64) * K + k0 + 32 + sch, &As2[srow + 64][sch]);
    async16(Bt + (size_t)(n0 + srow) * K + k0 + sch,           &Bs [srow][sch]);       // srow<64
    async16(Bt + (size_t)(n0 + srow) * K + k0 + 32 + sch,      &Bs2[srow][sch]);
    __syncthreads();
    bf16x8 af[4], bfr[2];
#pragma unroll
    for (int i = 0; i < 4; ++i)
      af[i] = *(const bf16x8*)&As[wm + i * 16 + l16][quad * 8];
#pragma unroll
    for (int i = 0; i < 2; ++i)
      bfr[i] = *(const bf16x8*)&Bs[wn + i * 16 + l16][quad * 8];
#pragma unroll
    for (int mi = 0; mi < 4; ++mi)
#pragma unroll
      for (int ni = 0; ni < 2; ++ni)
        acc[mi][ni] = __builtin_amdgcn_mfma_f32_16x16x32_bf16(af[mi], bfr[ni], acc[mi][ni], 0, 0, 0);
#pragma unroll
    for (int i = 0; i < 4; ++i)
      af[i] = *(const bf16x8*)&As2[wm + i * 16 + l16][quad * 8];
#pragma unroll
    for (int i = 0; i < 2; ++i)
      bfr[i] = *(const bf16x8*)&Bs2[wn + i * 16 + l16][quad * 8];
#pragma unroll
    for (int mi = 0; mi < 4; ++mi)
#pragma unroll
      for (int ni = 0; ni < 2; ++ni)
        acc[mi][ni] = __builtin_amdgcn_mfma_f32_16x16x32_bf16(af[mi], bfr[ni], acc[mi][ni], 0, 0, 0);
  }
#pragma unroll
  for (int mi = 0; mi < 4; ++mi)
#pragma unroll
    for (int ni = 0; ni < 2; ++ni) {
      const int col = n0 + wn + ni * 16 + l16;
      const float bv = bias[col];
      const int row0 = m0 + wm + mi * 16 + quad * 4;
#pragma unroll
      for (int r = 0; r < 4; ++r)
        C[(size_t)(row0 + r) * N + col] = acc[mi][ni][r] + bv;
    }
}

// ------- causal flash attention R21 (= R20 with LDS-offset fix): -------
// split-Q, K in LDS (double-buffered), V from global.
// R20's NaN: STAGE wrote the second K half at lb+4096 ELEMENTS (+8192 B) —
// past the 8 KB buffer (into Ks[1]/Pt) — leaving rows 32-63 unwritten. The
// correct offset is +2048 elements (+4096 B = rows 32-63). Global side was
// right. Everything else unchanged from R20's design:
//  - QBLK=64, grid 1024 (R19's QBLK=128 was grid/TLP-capped at 2 blocks/CU)
//  - K staged once per block via global_load_lds, XOR-swizzled rows
//    (linear LDS dest + inverse-swizzled global source, rule #21)
//  - V per-wave from global (L2-resident ~2MB/XCD), issued right after QK,
//    consumed after exp -> L2 latency hides under VALU
//  - LDS 25.6KB (Ks 16 + Pt 9); LDS read traffic/wave-tile 20KB -> 12KB
__global__ __launch_bounds__(256) void attn_kernel(
    const unsigned short* __restrict__ Qh, const unsigned short* __restrict__ Kh,
    const unsigned short* __restrict__ Vt, unsigned short* __restrict__ ctx) {
  const int id = blockIdx.x;                  // 1024 blocks
  const int j = id >> 3;                      // 0..127
  const int bh = (id & 7) | ((j & 3) << 3);   // id%8 constant per bh -> XCD-local
  const int s = 31 - (j >> 2);                // 64-query strip, long first
  const int b = bh >> 4, h = bh & 15;
  const int tid = threadIdx.x;
  const int wave = tid >> 6, lane = tid & 63;
  const int quad = lane >> 4, l16 = lane & 15;
  const int q0 = s * 64;
  const int T = s + 1;                        // 64-key tiles (causal)

  __shared__ unsigned short Ks[2][64][64];    // 16 KB, rows XOR-swizzled
  __shared__ unsigned short Pt[4][16][72];    // 9 KB, padded (conflict-free)

  const unsigned short* Qp = Qh + (size_t)bh * 2048 * 64;
  const unsigned short* Kg = Kh + (size_t)bh * 2048 * 64;
  const unsigned short* Vg = Vt + (size_t)bh * 64 * 2048;  // 32-key tile t2 at +t2*2048

  // hoisted STAGE addressing (rule #21: linear LDS dest, inverse-swizzled
  // global source). Thread stages rows r8 and r8+32; both share (row&7).
  const int r8 = tid >> 3;
  const int cswz = ((tid & 7) * 16) ^ ((r8 & 7) << 4);   // byte col
  const unsigned short* gK = Kg + (size_t)r8 * 64 + (cswz >> 1);
  unsigned short* lbK0 = &Ks[0][0][0] + tid * 8;
  unsigned short* lbK1 = &Ks[1][0][0] + tid * 8;

#define STAGE(bf_, t_)                                       \
  do {                                                       \
    const unsigned short* g = gK + (size_t)(t_) * 4096;      \
    unsigned short* lb = (bf_) ? lbK1 : lbK0;                \
    async16(g, lb);                                          \
    async16(g + 2048, lb + 2048);  /* rows 32-63: +4096 B */ \
  } while (0)

  // Q fragments: 16 queries per wave, B-frag n=query(l16), k=dim(quad*8+jj)
  bf16x8 qf[2];
#pragma unroll
  for (int kk = 0; kk < 2; ++kk)
    qf[kk] = *(const bf16x8*)(Qp + (size_t)(q0 + wave * 16 + l16) * 64 + kk * 32 + quad * 8);

  bf16x8 ones;  // A-frag of 1.0: l-row = 1^T P
#pragma unroll
  for (int jj = 0; jj < 8; ++jj) ones[jj] = (short)0x3F80;

  f32x4 o[5] = {};                    // [0..3]=O^T dg blocks, [4]=l row

  STAGE(0, 0);

  for (int t = 0; t < T; ++t) {
    const int cur = t & 1;
    const int k0 = t * 64;
    __syncthreads();                  // staged tile t visible; other buf free
    if (t + 1 < T) STAGE((t + 1) & 1, t + 1);   // in flight during compute

    // ---- S^T = K Q^T over 64 keys (K from LDS, swizzled reads) ----
    f32x4 st[4] = {};  // [keyg]
#pragma unroll
    for (int keyg = 0; keyg < 4; ++keyg) {
#pragma unroll
      for (int kk = 0; kk < 2; ++kk) {
        const int r = keyg * 16 + l16;
        const int cp = (kk * 64 + quad * 16) ^ ((r & 7) << 4);
        bf16x8 kf = *(const bf16x8*)&Ks[cur][r][cp >> 1];
        st[keyg] = __builtin_amdgcn_mfma_f32_16x16x32_bf16(kf, qf[kk], st[keyg], 0, 0, 0);
      }
    }
    // ---- V fragments from GLOBAL (issue early; L2-resident; consumed
    // after exp so ~200cy L2 latency hides under VALU work) ----
    bf16x8 vf[4][2];  // [dg][half]
#pragma unroll
    for (int dg = 0; dg < 4; ++dg)
#pragma unroll
      for (int half = 0; half < 2; ++half)
        vf[dg][half] = *(const bf16x8*)(Vg + (size_t)(2 * t + half) * 2048 + (dg * 16 + l16) * 32 + quad * 8);
    // ---- causal mask: only the diagonal (last) tile ----
    if (t == T - 1) {
#pragma unroll
      for (int keyg = 0; keyg < 4; ++keyg)
#pragma unroll
        for (int r = 0; r < 4; ++r) {
          const int key = k0 + keyg * 16 + quad * 4 + r;
          if (key > q0 + wave * 16 + l16) st[keyg][r] = -INFINITY;
        }
    }
    // ---- no-max softmax: p = exp2(s); pack bf16; stage P^T (wave-local) ----
#pragma unroll
    for (int keyg = 0; keyg < 4; ++keyg) {
      float p0 = exp2f(st[keyg][0]);
      float p1 = exp2f(st[keyg][1]);
      float p2 = exp2f(st[keyg][2]);
      float p3 = exp2f(st[keyg][3]);
      uint2 pk;  // truncate-to-bf16 pack via v_perm
      pk.x = __builtin_amdgcn_perm(fb(p1), fb(p0), 0x07060302u);
      pk.y = __builtin_amdgcn_perm(fb(p3), fb(p2), 0x07060302u);
      *(uint2*)&Pt[wave][l16][keyg * 16 + quad * 4] = pk;
    }
    bf16x8 pb[2];  // [half] — wave-local LDS roundtrip (in-order per wave)
#pragma unroll
    for (int half = 0; half < 2; ++half)
      pb[half] = *(const bf16x8*)&Pt[wave][l16][half * 32 + quad * 8];
    // ---- O^T += V^T P ; l-row += 1^T P ----
#pragma unroll
    for (int dg = 0; dg < 4; ++dg) {
      o[dg] = __builtin_amdgcn_mfma_f32_16x16x32_bf16(vf[dg][0], pb[0], o[dg], 0, 0, 0);
      o[dg] = __builtin_amdgcn_mfma_f32_16x16x32_bf16(vf[dg][1], pb[1], o[dg], 0, 0, 0);
    }
    o[4] = __builtin_amdgcn_mfma_f32_16x16x32_bf16(ones, pb[0], o[4], 0, 0, 0);
    o[4] = __builtin_amdgcn_mfma_f32_16x16x32_bf16(ones, pb[1], o[4], 0, 0, 0);
  }
#undef STAGE

  // ---- epilogue: no merge — wave owns its 16 queries entirely ----
  const float inv = 1.f / o[4][0];
  const size_t base = (size_t)(b * 2048 + q0 + wave * 16 + l16) * 1024 + h * 64;
#pragma unroll
  for (int dg = 0; dg < 4; ++dg) {
    ushort4 us;
    us.x = f2bf(o[dg][0] * inv); us.y = f2bf(o[dg][1] * inv);
    us.z = f2bf(o[dg][2] * inv); us.w = f2bf(o[dg][3] * inv);
    *(ushort4*)&ctx[base + dg * 16 + quad * 4] = us;
  }
}

// ---------------- launch ----------------
extern "C" void kernel_launch(void* const* d_in, const int* in_sizes, int n_in,
                              void* d_out, int out_size, void* d_ws, size_t ws_size,
                              hipStream_t stream) {
  const float* x  = (const float*)d_in[0];
  const float* Wq = (const float*)d_in[1];
  const float* Wk = (const float*)d_in[2];
  const float* Wv = (const float*)d_in[3];
  const float* Wo = (const float*)d_in[4];
  const float* bo = (const float*)d_in[5];
  float* out = (float*)d_out;

  // workspace layout (48 MB total)
  char* ws = (char*)d_ws;
  unsigned short* Xb    = (unsigned short*)(ws);                          //  8 MB [4096][1024]
  unsigned short* Wqkvt = (unsigned short*)(ws + (size_t)8  * 1048576);   //  6 MB [3072][1024]
  unsigned short* Wot   = (unsigned short*)(ws + (size_t)14 * 1048576);   //  2 MB [1024][1024]
  unsigned short* Qhb   = (unsigned short*)(ws + (size_t)16 * 1048576);   //  8 MB [32][2048][64]
  unsigned short* Khb   = (unsigned short*)(ws + (size_t)24 * 1048576);   //  8 MB [32][2048][64]
  unsigned short* Vtb   = (unsigned short*)(ws + (size_t)32 * 1048576);   //  8 MB [32][64][64][32]
  unsigned short* CT    = (unsigned short*)(ws + (size_t)40 * 1048576);   //  8 MB [4096][1024]

  prep_kernel<<<dim3(32, 32, 5), 256, 0, stream>>>(x, Wq, Wk, Wv, Wo, Xb, Wqkvt, Wot);
  gemm_qkv<<<768, 256, 0, stream>>>(Xb, Wqkvt, Qhb, Khb, Vtb, 1024);
  attn_kernel<<<1024, 256, 0, stream>>>(Qhb, Khb, Vtb, CT);
  gemm_out<<<512, 256, 0, stream>>>(CT, Wot, out, bo, 1024, 1024);
}

// Round 10
// 170.916 us; speedup vs baseline: 1.1225x; 1.1225x over previous
//
#include <hip/hip_runtime.h>
#include <hip/hip_bf16.h>
#include <math.h>

typedef __attribute__((ext_vector_type(8))) short bf16x8;
typedef __attribute__((ext_vector_type(8))) unsigned short u16x8;
typedef __attribute__((ext_vector_type(4))) float f32x4;

__device__ __forceinline__ unsigned short f2bf(float f) {
  union { float f; unsigned u; } c; c.f = f;
  unsigned u = c.u;
  u += 0x7fffu + ((u >> 16) & 1u);   // round-to-nearest-even
  return (unsigned short)(u >> 16);
}
__device__ __forceinline__ unsigned fb(float x) {
  union { float f; unsigned u; } c; c.f = x; return c.u;
}
// async global->LDS, 16B per lane; LDS dest must be wave-uniform base + lane*16
__device__ __forceinline__ void async16(const unsigned short* g, unsigned short* l) {
  __builtin_amdgcn_global_load_lds(
      (const __attribute__((address_space(1))) unsigned int*)g,
      (__attribute__((address_space(3))) unsigned int*)l, 16, 0, 0);
}

// -------- fused prep: z<4 transpose+cast weights (z=0 Wq scaled by C); z=4 cast x --------
__global__ __launch_bounds__(256) void prep_kernel(
    const float* __restrict__ x, const float* __restrict__ Wq,
    const float* __restrict__ Wk, const float* __restrict__ Wv,
    const float* __restrict__ Wo, unsigned short* __restrict__ Xb,
    unsigned short* __restrict__ Wqkvt, unsigned short* __restrict__ Wot) {
  const int z = blockIdx.z;
  if (z == 4) {  // cast x: 1M float4 over 1024 blocks, 4 float4/thread
    const int bid = blockIdx.y * 32 + blockIdx.x;
#pragma unroll
    for (int i = 0; i < 4; ++i) {
      const int idx = (bid * 4 + i) * 256 + threadIdx.x;
      float4 v = ((const float4*)x)[idx];
      ushort4 o;
      o.x = f2bf(v.x); o.y = f2bf(v.y); o.z = f2bf(v.z); o.w = f2bf(v.w);
      ((ushort4*)Xb)[idx] = o;
    }
    return;
  }
  __shared__ float t[32][33];
  const float* src = (z == 0) ? Wq : (z == 1) ? Wk : (z == 2) ? Wv : Wo;
  unsigned short* dst = (z < 3) ? (Wqkvt + (size_t)z * 1024 * 1024) : Wot;
  const float scale = (z == 0) ? 0.18033688f : 1.0f;  // log2(e)/sqrt(64) into Wq
  int tx = threadIdx.x & 31, ty = threadIdx.x >> 5;
  int bx = blockIdx.x, by = blockIdx.y;
#pragma unroll
  for (int i = 0; i < 4; ++i)
    t[ty + i * 8][tx] = src[(size_t)(by * 32 + ty + i * 8) * 1024 + bx * 32 + tx];
  __syncthreads();
#pragma unroll
  for (int i = 0; i < 4; ++i)
    dst[(size_t)(bx * 32 + ty + i * 8) * 1024 + by * 32 + tx] = f2bf(t[tx][ty + i * 8] * scale);
}

// ---------------- QKV GEMM: 128x128 tile, BK=64, XCD-swizzled ----------------
// (epilogue = exact R11 form; Q-scale lives in the weights now)
__global__ __launch_bounds__(256) void gemm_qkv(
    const unsigned short* __restrict__ A, const unsigned short* __restrict__ Bt,
    unsigned short* __restrict__ Qh, unsigned short* __restrict__ Kh,
    unsigned short* __restrict__ Vt, int K) {
  __shared__ unsigned short As [128][32];  // unpadded: global_load_lds lane ordering
  __shared__ unsigned short As2[128][32];
  __shared__ unsigned short Bs [128][32];
  __shared__ unsigned short Bs2[128][32];
  const int flat = blockIdx.x;
  const int xcd = flat & 7, idx = flat >> 3;      // 96 blocks per XCD
  const int mg = xcd >> 1, ng = xcd & 1;          // 4x2 XCD rectangle grid
  const int m0 = (mg * 8 + (idx & 7)) * 128;      // 32 m-tiles
  const int n0 = (ng * 12 + (idx >> 3)) * 128;    // 24 n-tiles
  const int tid = threadIdx.x;
  const int wave = tid >> 6, lane = tid & 63;
  const int quad = lane >> 4, l16 = lane & 15;
  const int wm = (wave >> 1) * 64, wn = (wave & 1) * 64;
  const int srow = tid >> 2, sch = (tid & 3) * 8;  // LDS byte addr = tid*16
  f32x4 acc[4][4] = {};

  for (int k0 = 0; k0 < K; k0 += 64) {
    __syncthreads();
    async16(A  + (size_t)(m0 + srow) * K + k0 + sch,           &As [srow][sch]);
    async16(A  + (size_t)(m0 + srow + 64) * K + k0 + sch,      &As [srow + 64][sch]);
    async16(A  + (size_t)(m0 + srow) * K + k0 + 32 + sch,      &As2[srow][sch]);
    async16(A  + (size_t)(m0 + srow + 64) * K + k0 + 32 + sch, &As2[srow + 64][sch]);
    async16(Bt + (size_t)(n0 + srow) * K + k0 + sch,           &Bs [srow][sch]);
    async16(Bt + (size_t)(n0 + srow + 64) * K + k0 + sch,      &Bs [srow + 64][sch]);
    async16(Bt + (size_t)(n0 + srow) * K + k0 + 32 + sch,      &Bs2[srow][sch]);
    async16(Bt + (size_t)(n0 + srow + 64) * K + k0 + 32 + sch, &Bs2[srow + 64][sch]);
    __syncthreads();
    bf16x8 af[4], bfr[4];
#pragma unroll
    for (int i = 0; i < 4; ++i) {
      af[i]  = *(const bf16x8*)&As[wm + i * 16 + l16][quad * 8];
      bfr[i] = *(const bf16x8*)&Bs[wn + i * 16 + l16][quad * 8];
    }
#pragma unroll
    for (int mi = 0; mi < 4; ++mi)
#pragma unroll
      for (int ni = 0; ni < 4; ++ni)
        acc[mi][ni] = __builtin_amdgcn_mfma_f32_16x16x32_bf16(af[mi], bfr[ni], acc[mi][ni], 0, 0, 0);
#pragma unroll
    for (int i = 0; i < 4; ++i) {
      af[i]  = *(const bf16x8*)&As2[wm + i * 16 + l16][quad * 8];
      bfr[i] = *(const bf16x8*)&Bs2[wn + i * 16 + l16][quad * 8];
    }
#pragma unroll
    for (int mi = 0; mi < 4; ++mi)
#pragma unroll
      for (int ni = 0; ni < 4; ++ni)
        acc[mi][ni] = __builtin_amdgcn_mfma_f32_16x16x32_bf16(af[mi], bfr[ni], acc[mi][ni], 0, 0, 0);
  }

#pragma unroll
  for (int mi = 0; mi < 4; ++mi) {
#pragma unroll
    for (int ni = 0; ni < 4; ++ni) {
      const int col = n0 + wn + ni * 16 + l16;
      const int token0 = m0 + wm + mi * 16 + quad * 4;
      const int bb = token0 >> 11, s0 = token0 & 2047;
      if (col < 2048) {  // Q or K, head-major [bh][s][64]
        const int hh = (col & 1023) >> 6, d = col & 63;
        unsigned short* dst = (col < 1024) ? Qh : Kh;
        dst += ((size_t)(bb * 16 + hh) * 2048 + s0) * 64 + d;
#pragma unroll
        for (int r = 0; r < 4; ++r) dst[(size_t)r * 64] = f2bf(acc[mi][ni][r]);
      } else {           // V, tiled [bh][s>>5][d][32]
        const int vc = col - 2048, hh = vc >> 6, d = vc & 63;
        ushort4 us;
        us.x = f2bf(acc[mi][ni][0]); us.y = f2bf(acc[mi][ni][1]);
        us.z = f2bf(acc[mi][ni][2]); us.w = f2bf(acc[mi][ni][3]);
        *(ushort4*)&Vt[(((size_t)(bb * 16 + hh) * 64 + (s0 >> 5)) * 64 + d) * 32 + (s0 & 31)] = us;
      }
    }
  }
}

// ---------------- output GEMM: 128x64 tile, BK=64, XCD-swizzled ----------------
__global__ __launch_bounds__(256) void gemm_out(
    const unsigned short* __restrict__ A, const unsigned short* __restrict__ Bt,
    float* __restrict__ C, const float* __restrict__ bias, int N, int K) {
  __shared__ unsigned short As [128][32];
  __shared__ unsigned short As2[128][32];
  __shared__ unsigned short Bs [64][32];
  __shared__ unsigned short Bs2[64][32];
  const int flat = blockIdx.x;
  const int xcd = flat & 7, idx = flat >> 3;      // 64 blocks per XCD
  const int mg = xcd >> 1, ng = xcd & 1;
  const int m0 = (mg * 8 + (idx & 7)) * 128;      // 32 m-tiles
  const int n0 = (ng * 8 + (idx >> 3)) * 64;      // 16 n-tiles
  const int tid = threadIdx.x;
  const int wave = tid >> 6, lane = tid & 63;
  const int quad = lane >> 4, l16 = lane & 15;
  const int wm = (wave >> 1) * 64, wn = (wave & 1) * 32;
  const int srow = tid >> 2, sch = (tid & 3) * 8;
  f32x4 acc[4][2] = {};

  for (int k0 = 0; k0 < K; k0 += 64) {
    __syncthreads();
    async16(A  + (size_t)(m0 + srow) * K + k0 + sch,           &As [srow][sch]);
    async16(A  + (size_t)(m0 + srow + 64) * K + k0 + sch,      &As [srow + 64][sch]);
    async16(A  + (size_t)(m0 + srow) * K + k0 + 32 + sch,      &As2[srow][sch]);
    async16(A  + (size_t)(m0 + srow + 64) * K + k0 + 32 + sch, &As2[srow + 64][sch]);
    async16(Bt + (size_t)(n0 + srow) * K + k0 + sch,           &Bs [srow][sch]);       // srow<64
    async16(Bt + (size_t)(n0 + srow) * K + k0 + 32 + sch,      &Bs2[srow][sch]);
    __syncthreads();
    bf16x8 af[4], bfr[2];
#pragma unroll
    for (int i = 0; i < 4; ++i)
      af[i] = *(const bf16x8*)&As[wm + i * 16 + l16][quad * 8];
#pragma unroll
    for (int i = 0; i < 2; ++i)
      bfr[i] = *(const bf16x8*)&Bs[wn + i * 16 + l16][quad * 8];
#pragma unroll
    for (int mi = 0; mi < 4; ++mi)
#pragma unroll
      for (int ni = 0; ni < 2; ++ni)
        acc[mi][ni] = __builtin_amdgcn_mfma_f32_16x16x32_bf16(af[mi], bfr[ni], acc[mi][ni], 0, 0, 0);
#pragma unroll
    for (int i = 0; i < 4; ++i)
      af[i] = *(const bf16x8*)&As2[wm + i * 16 + l16][quad * 8];
#pragma unroll
    for (int i = 0; i < 2; ++i)
      bfr[i] = *(const bf16x8*)&Bs2[wn + i * 16 + l16][quad * 8];
#pragma unroll
    for (int mi = 0; mi < 4; ++mi)
#pragma unroll
      for (int ni = 0; ni < 2; ++ni)
        acc[mi][ni] = __builtin_amdgcn_mfma_f32_16x16x32_bf16(af[mi], bfr[ni], acc[mi][ni], 0, 0, 0);
  }
#pragma unroll
  for (int mi = 0; mi < 4; ++mi)
#pragma unroll
    for (int ni = 0; ni < 2; ++ni) {
      const int col = n0 + wn + ni * 16 + l16;
      const float bv = bias[col];
      const int row0 = m0 + wm + mi * 16 + quad * 4;
#pragma unroll
      for (int r = 0; r < 4; ++r)
        C[(size_t)(row0 + r) * N + col] = acc[mi][ni][r] + bv;
    }
}

// ------- causal flash attention R22: R18 structure + 4-blocks/CU fit -------
// R18 (split-Q, K+V staged in LDS, 1 barrier/tile) = best at 43.7us. R21
// proved V must stay in LDS (global V regressed 22us). R18's LDS was 41984B
// -> only 3 blocks/CU (160K/41984); the grid offers 4. R22 shrinks LDS to
// exactly 40960B (= 4 x 40960 = 160KB exact):
//  - Pt[4][16][72] (9216B, padded) -> Pt[4][16][64] (8192B) with XOR swizzle
//    ecol ^= (l16&7)<<3 on write+read (<=4-way conflicts on 6 ops/tile, free-ish)
//  - STAGE addressing hoisted (R19's proven-correct pointer set: all 4 global
//    sources advance exactly 4096 elems/tile; LDS dest tid*16B + i*4096B)
// Everything else byte-identical to R18: QBLK=64, grid 1024, no merge tree,
// no-max exp2 softmax, swizzled K/V rows, 16x16x32 MFMA.
__global__ __launch_bounds__(256) void attn_kernel(
    const unsigned short* __restrict__ Qh, const unsigned short* __restrict__ Kh,
    const unsigned short* __restrict__ Vt, unsigned short* __restrict__ ctx) {
  const int id = blockIdx.x;                  // 1024 blocks
  const int j = id >> 3;                      // 0..127
  const int bh = (id & 7) | ((j & 3) << 3);   // id%8 constant per bh -> XCD-local
  const int s = 31 - (j >> 2);                // 64-query strip, long strips first
  const int b = bh >> 4, h = bh & 15;
  const int tid = threadIdx.x;
  const int wave = tid >> 6, lane = tid & 63;
  const int quad = lane >> 4, l16 = lane & 15;
  const int q0 = s * 64;
  const int T = s + 1;                        // 64-key tiles (causal)

  // KV[buf][row][col]: rows 0-63 = K keys, 64-127 = V d-rows; 128B rows,
  // XOR-swizzled (byte col ^= (row&7)<<4). Pt: unpadded, XOR-swizzled.
  __shared__ unsigned short KV[2][128][64];   // 32768 B
  __shared__ unsigned short Pt[4][16][64];    //  8192 B  (total 40960 = 4/CU)

  const unsigned short* Qp = Qh + (size_t)bh * 2048 * 64;
  const unsigned short* Kg = Kh + (size_t)bh * 2048 * 64;
  const unsigned short* Vg = Vt + (size_t)bh * 64 * 2048;  // 32-key tile t2 at +t2*2048

  // hoisted STAGE addressing (rule #21: linear LDS dest, inverse-swizzled
  // global source). Proven correct in R19. All sources advance 4096 elems/tile.
  const int swzc = ((tid & 7) * 16) ^ (((tid >> 3) & 7) << 4);  // byte col
  const int r32 = tid >> 3;                   // row within 32-row group
  const unsigned short* gK0 = Kg + (size_t)r32 * 64 + (swzc >> 1);
  const unsigned short* gK1 = gK0 + 32 * 64;
  const int vkey = swzc >> 1;
  const unsigned short* gV0 = Vg + (size_t)(vkey >> 5) * 2048 + r32 * 32 + (vkey & 31);
  const unsigned short* gV1 = gV0 + 32 * 32;  // d += 32
  unsigned short* lb0 = &KV[0][0][0] + tid * 8;
  unsigned short* lb1 = &KV[1][0][0] + tid * 8;

#define STAGE(bf_, t_)                                      \
  do {                                                      \
    const size_t toff = (size_t)(t_) * 4096;                \
    unsigned short* lb = (bf_) ? lb1 : lb0;                 \
    async16(gK0 + toff, lb);                                \
    async16(gK1 + toff, lb + 2048);                         \
    async16(gV0 + toff, lb + 4096);                         \
    async16(gV1 + toff, lb + 6144);                         \
  } while (0)

  // Q fragments: 16 queries per wave, B-frag n=query(l16), k=dim(quad*8+jj)
  bf16x8 qf[2];
#pragma unroll
  for (int kk = 0; kk < 2; ++kk)
    qf[kk] = *(const bf16x8*)(Qp + (size_t)(q0 + wave * 16 + l16) * 64 + kk * 32 + quad * 8);

  bf16x8 ones;  // A-frag of 1.0: l-row = 1^T P
#pragma unroll
  for (int jj = 0; jj < 8; ++jj) ones[jj] = (short)0x3F80;

  f32x4 o[5] = {};                    // [0..3]=O^T dg blocks, [4]=l row

  const int psw = (l16 & 7) << 3;     // Pt element-col swizzle for this lane

  STAGE(0, 0);

  for (int t = 0; t < T; ++t) {
    const int cur = t & 1;
    const int k0 = t * 64;
    __syncthreads();                  // staged tile t visible; other buf free
    if (t + 1 < T) STAGE((t + 1) & 1, t + 1);   // in flight during compute

    // ---- S^T = K Q^T over 64 keys (K from LDS, swizzled reads) ----
    f32x4 st[4] = {};  // [keyg]
#pragma unroll
    for (int keyg = 0; keyg < 4; ++keyg) {
#pragma unroll
      for (int kk = 0; kk < 2; ++kk) {
        const int r = keyg * 16 + l16;
        const int cp = (kk * 64 + quad * 16) ^ ((r & 7) << 4);
        bf16x8 kf = *(const bf16x8*)&KV[cur][r][cp >> 1];
        st[keyg] = __builtin_amdgcn_mfma_f32_16x16x32_bf16(kf, qf[kk], st[keyg], 0, 0, 0);
      }
    }
    // ---- V fragments from LDS (cheap ds_reads; consumed after exp) ----
    bf16x8 vf[4][2];  // [dg][half]
#pragma unroll
    for (int dg = 0; dg < 4; ++dg)
#pragma unroll
      for (int half = 0; half < 2; ++half) {
        const int row = 64 + dg * 16 + l16;
        const int cp = (half * 64 + quad * 16) ^ ((row & 7) << 4);
        vf[dg][half] = *(const bf16x8*)&KV[cur][row][cp >> 1];
      }
    // ---- causal mask: only the diagonal (last) tile ----
    if (t == T - 1) {
#pragma unroll
      for (int keyg = 0; keyg < 4; ++keyg)
#pragma unroll
        for (int r = 0; r < 4; ++r) {
          const int key = k0 + keyg * 16 + quad * 4 + r;
          if (key > q0 + wave * 16 + l16) st[keyg][r] = -INFINITY;
        }
    }
    // ---- no-max softmax: p = exp2(s); pack bf16; stage P^T (wave-local,
    //      XOR-swizzled cols) ----
#pragma unroll
    for (int keyg = 0; keyg < 4; ++keyg) {
      float p0 = exp2f(st[keyg][0]);
      float p1 = exp2f(st[keyg][1]);
      float p2 = exp2f(st[keyg][2]);
      float p3 = exp2f(st[keyg][3]);
      uint2 pk;  // truncate-to-bf16 pack via v_perm
      pk.x = __builtin_amdgcn_perm(fb(p1), fb(p0), 0x07060302u);
      pk.y = __builtin_amdgcn_perm(fb(p3), fb(p2), 0x07060302u);
      *(uint2*)&Pt[wave][l16][(keyg * 16 + quad * 4) ^ psw] = pk;
    }
    bf16x8 pb[2];  // [half] — wave-local LDS roundtrip (in-order per wave)
#pragma unroll
    for (int half = 0; half < 2; ++half)
      pb[half] = *(const bf16x8*)&Pt[wave][l16][(half * 32 + quad * 8) ^ psw];
    // ---- O^T += V^T P ; l-row += 1^T P ----
#pragma unroll
    for (int dg = 0; dg < 4; ++dg) {
      o[dg] = __builtin_amdgcn_mfma_f32_16x16x32_bf16(vf[dg][0], pb[0], o[dg], 0, 0, 0);
      o[dg] = __builtin_amdgcn_mfma_f32_16x16x32_bf16(vf[dg][1], pb[1], o[dg], 0, 0, 0);
    }
    o[4] = __builtin_amdgcn_mfma_f32_16x16x32_bf16(ones, pb[0], o[4], 0, 0, 0);
    o[4] = __builtin_amdgcn_mfma_f32_16x16x32_bf16(ones, pb[1], o[4], 0, 0, 0);
  }
#undef STAGE

  // ---- epilogue: no merge — wave owns its 16 queries entirely ----
  const float inv = 1.f / o[4][0];
  const size_t base = (size_t)(b * 2048 + q0 + wave * 16 + l16) * 1024 + h * 64;
#pragma unroll
  for (int dg = 0; dg < 4; ++dg) {
    ushort4 us;
    us.x = f2bf(o[dg][0] * inv); us.y = f2bf(o[dg][1] * inv);
    us.z = f2bf(o[dg][2] * inv); us.w = f2bf(o[dg][3] * inv);
    *(ushort4*)&ctx[base + dg * 16 + quad * 4] = us;
  }
}

// ---------------- launch ----------------
extern "C" void kernel_launch(void* const* d_in, const int* in_sizes, int n_in,
                              void* d_out, int out_size, void* d_ws, size_t ws_size,
                              hipStream_t stream) {
  const float* x  = (const float*)d_in[0];
  const float* Wq = (const float*)d_in[1];
  const float* Wk = (const float*)d_in[2];
  const float* Wv = (const float*)d_in[3];
  const float* Wo = (const float*)d_in[4];
  const float* bo = (const float*)d_in[5];
  float* out = (float*)d_out;

  // workspace layout (48 MB total)
  char* ws = (char*)d_ws;
  unsigned short* Xb    = (unsigned short*)(ws);                          //  8 MB [4096][1024]
  unsigned short* Wqkvt = (unsigned short*)(ws + (size_t)8  * 1048576);   //  6 MB [3072][1024]
  unsigned short* Wot   = (unsigned short*)(ws + (size_t)14 * 1048576);   //  2 MB [1024][1024]
  unsigned short* Qhb   = (unsigned short*)(ws + (size_t)16 * 1048576);   //  8 MB [32][2048][64]
  unsigned short* Khb   = (unsigned short*)(ws + (size_t)24 * 1048576);   //  8 MB [32][2048][64]
  unsigned short* Vtb   = (unsigned short*)(ws + (size_t)32 * 1048576);   //  8 MB [32][64][64][32]
  unsigned short* CT    = (unsigned short*)(ws + (size_t)40 * 1048576);   //  8 MB [4096][1024]

  prep_kernel<<<dim3(32, 32, 5), 256, 0, stream>>>(x, Wq, Wk, Wv, Wo, Xb, Wqkvt, Wot);
  gemm_qkv<<<768, 256, 0, stream>>>(Xb, Wqkvt, Qhb, Khb, Vtb, 1024);
  attn_kernel<<<1024, 256, 0, stream>>>(Qhb, Khb, Vtb, CT);
  gemm_out<<<512, 256, 0, stream>>>(CT, Wot, out, bo, 1024, 1024);
}

// Round 11
// 167.017 us; speedup vs baseline: 1.1487x; 1.0233x over previous
//
#include <hip/hip_runtime.h>
#include <hip/hip_bf16.h>
#include <math.h>

typedef __attribute__((ext_vector_type(8))) short bf16x8;
typedef __attribute__((ext_vector_type(8))) unsigned short u16x8;
typedef __attribute__((ext_vector_type(4))) float f32x4;

__device__ __forceinline__ unsigned short f2bf(float f) {
  union { float f; unsigned u; } c; c.f = f;
  unsigned u = c.u;
  u += 0x7fffu + ((u >> 16) & 1u);   // round-to-nearest-even
  return (unsigned short)(u >> 16);
}
__device__ __forceinline__ unsigned fb(float x) {
  union { float f; unsigned u; } c; c.f = x; return c.u;
}
// async global->LDS, 16B per lane; LDS dest must be wave-uniform base + lane*16
__device__ __forceinline__ void async16(const unsigned short* g, unsigned short* l) {
  __builtin_amdgcn_global_load_lds(
      (const __attribute__((address_space(1))) unsigned int*)g,
      (__attribute__((address_space(3))) unsigned int*)l, 16, 0, 0);
}

// -------- fused prep: z<4 transpose+cast weights (z=0 Wq scaled by C); z=4 cast x --------
__global__ __launch_bounds__(256) void prep_kernel(
    const float* __restrict__ x, const float* __restrict__ Wq,
    const float* __restrict__ Wk, const float* __restrict__ Wv,
    const float* __restrict__ Wo, unsigned short* __restrict__ Xb,
    unsigned short* __restrict__ Wqkvt, unsigned short* __restrict__ Wot) {
  const int z = blockIdx.z;
  if (z == 4) {  // cast x: 1M float4 over 1024 blocks, 4 float4/thread
    const int bid = blockIdx.y * 32 + blockIdx.x;
#pragma unroll
    for (int i = 0; i < 4; ++i) {
      const int idx = (bid * 4 + i) * 256 + threadIdx.x;
      float4 v = ((const float4*)x)[idx];
      ushort4 o;
      o.x = f2bf(v.x); o.y = f2bf(v.y); o.z = f2bf(v.z); o.w = f2bf(v.w);
      ((ushort4*)Xb)[idx] = o;
    }
    return;
  }
  __shared__ float t[32][33];
  const float* src = (z == 0) ? Wq : (z == 1) ? Wk : (z == 2) ? Wv : Wo;
  unsigned short* dst = (z < 3) ? (Wqkvt + (size_t)z * 1024 * 1024) : Wot;
  const float scale = (z == 0) ? 0.18033688f : 1.0f;  // log2(e)/sqrt(64) into Wq
  int tx = threadIdx.x & 31, ty = threadIdx.x >> 5;
  int bx = blockIdx.x, by = blockIdx.y;
#pragma unroll
  for (int i = 0; i < 4; ++i)
    t[ty + i * 8][tx] = src[(size_t)(by * 32 + ty + i * 8) * 1024 + bx * 32 + tx];
  __syncthreads();
#pragma unroll
  for (int i = 0; i < 4; ++i)
    dst[(size_t)(bx * 32 + ty + i * 8) * 1024 + by * 32 + tx] = f2bf(t[tx][ty + i * 8] * scale);
}

// ---------------- QKV GEMM: 128x128 tile, BK=64, XCD-swizzled ----------------
// (epilogue = exact R11 form; Q-scale lives in the weights now)
__global__ __launch_bounds__(256) void gemm_qkv(
    const unsigned short* __restrict__ A, const unsigned short* __restrict__ Bt,
    unsigned short* __restrict__ Qh, unsigned short* __restrict__ Kh,
    unsigned short* __restrict__ Vt, int K) {
  __shared__ unsigned short As [128][32];  // unpadded: global_load_lds lane ordering
  __shared__ unsigned short As2[128][32];
  __shared__ unsigned short Bs [128][32];
  __shared__ unsigned short Bs2[128][32];
  const int flat = blockIdx.x;
  const int xcd = flat & 7, idx = flat >> 3;      // 96 blocks per XCD
  const int mg = xcd >> 1, ng = xcd & 1;          // 4x2 XCD rectangle grid
  const int m0 = (mg * 8 + (idx & 7)) * 128;      // 32 m-tiles
  const int n0 = (ng * 12 + (idx >> 3)) * 128;    // 24 n-tiles
  const int tid = threadIdx.x;
  const int wave = tid >> 6, lane = tid & 63;
  const int quad = lane >> 4, l16 = lane & 15;
  const int wm = (wave >> 1) * 64, wn = (wave & 1) * 64;
  const int srow = tid >> 2, sch = (tid & 3) * 8;  // LDS byte addr = tid*16
  f32x4 acc[4][4] = {};

  for (int k0 = 0; k0 < K; k0 += 64) {
    __syncthreads();
    async16(A  + (size_t)(m0 + srow) * K + k0 + sch,           &As [srow][sch]);
    async16(A  + (size_t)(m0 + srow + 64) * K + k0 + sch,      &As [srow + 64][sch]);
    async16(A  + (size_t)(m0 + srow) * K + k0 + 32 + sch,      &As2[srow][sch]);
    async16(A  + (size_t)(m0 + srow + 64) * K + k0 + 32 + sch, &As2[srow + 64][sch]);
    async16(Bt + (size_t)(n0 + srow) * K + k0 + sch,           &Bs [srow][sch]);
    async16(Bt + (size_t)(n0 + srow + 64) * K + k0 + sch,      &Bs [srow + 64][sch]);
    async16(Bt + (size_t)(n0 + srow) * K + k0 + 32 + sch,      &Bs2[srow][sch]);
    async16(Bt + (size_t)(n0 + srow + 64) * K + k0 + 32 + sch, &Bs2[srow + 64][sch]);
    __syncthreads();
    bf16x8 af[4], bfr[4];
#pragma unroll
    for (int i = 0; i < 4; ++i) {
      af[i]  = *(const bf16x8*)&As[wm + i * 16 + l16][quad * 8];
      bfr[i] = *(const bf16x8*)&Bs[wn + i * 16 + l16][quad * 8];
    }
#pragma unroll
    for (int mi = 0; mi < 4; ++mi)
#pragma unroll
      for (int ni = 0; ni < 4; ++ni)
        acc[mi][ni] = __builtin_amdgcn_mfma_f32_16x16x32_bf16(af[mi], bfr[ni], acc[mi][ni], 0, 0, 0);
#pragma unroll
    for (int i = 0; i < 4; ++i) {
      af[i]  = *(const bf16x8*)&As2[wm + i * 16 + l16][quad * 8];
      bfr[i] = *(const bf16x8*)&Bs2[wn + i * 16 + l16][quad * 8];
    }
#pragma unroll
    for (int mi = 0; mi < 4; ++mi)
#pragma unroll
      for (int ni = 0; ni < 4; ++ni)
        acc[mi][ni] = __builtin_amdgcn_mfma_f32_16x16x32_bf16(af[mi], bfr[ni], acc[mi][ni], 0, 0, 0);
  }

#pragma unroll
  for (int mi = 0; mi < 4; ++mi) {
#pragma unroll
    for (int ni = 0; ni < 4; ++ni) {
      const int col = n0 + wn + ni * 16 + l16;
      const int token0 = m0 + wm + mi * 16 + quad * 4;
      const int bb = token0 >> 11, s0 = token0 & 2047;
      if (col < 2048) {  // Q or K, head-major [bh][s][64]
        const int hh = (col & 1023) >> 6, d = col & 63;
        unsigned short* dst = (col < 1024) ? Qh : Kh;
        dst += ((size_t)(bb * 16 + hh) * 2048 + s0) * 64 + d;
#pragma unroll
        for (int r = 0; r < 4; ++r) dst[(size_t)r * 64] = f2bf(acc[mi][ni][r]);
      } else {           // V, tiled [bh][s>>5][d][32]
        const int vc = col - 2048, hh = vc >> 6, d = vc & 63;
        ushort4 us;
        us.x = f2bf(acc[mi][ni][0]); us.y = f2bf(acc[mi][ni][1]);
        us.z = f2bf(acc[mi][ni][2]); us.w = f2bf(acc[mi][ni][3]);
        *(ushort4*)&Vt[(((size_t)(bb * 16 + hh) * 64 + (s0 >> 5)) * 64 + d) * 32 + (s0 & 31)] = us;
      }
    }
  }
}

// ---------------- output GEMM: 128x64 tile, BK=64, XCD-swizzled ----------------
__global__ __launch_bounds__(256) void gemm_out(
    const unsigned short* __restrict__ A, const unsigned short* __restrict__ Bt,
    float* __restrict__ C, const float* __restrict__ bias, int N, int K) {
  __shared__ unsigned short As [128][32];
  __shared__ unsigned short As2[128][32];
  __shared__ unsigned short Bs [64][32];
  __shared__ unsigned short Bs2[64][32];
  const int flat = blockIdx.x;
  const int xcd = flat & 7, idx = flat >> 3;      // 64 blocks per XCD
  const int mg = xcd >> 1, ng = xcd & 1;
  const int m0 = (mg * 8 + (idx & 7)) * 128;      // 32 m-tiles
  const int n0 = (ng * 8 + (idx >> 3)) * 64;      // 16 n-tiles
  const int tid = threadIdx.x;
  const int wave = tid >> 6, lane = tid & 63;
  const int quad = lane >> 4, l16 = lane & 15;
  const int wm = (wave >> 1) * 64, wn = (wave & 1) * 32;
  const int srow = tid >> 2, sch = (tid & 3) * 8;
  f32x4 acc[4][2] = {};

  for (int k0 = 0; k0 < K; k0 += 64) {
    __syncthreads();
    async16(A  + (size_t)(m0 + srow) * K + k0 + sch,           &As [srow][sch]);
    async16(A  + (size_t)(m0 + srow + 64) * K + k0 + sch,      &As [srow + 64][sch]);
    async16(A  + (size_t)(m0 + srow) * K + k0 + 32 + sch,      &As2[srow][sch]);
    async16(A  + (size_t)(m0 + srow + 64) * K + k0 + 32 + sch, &As2[srow + 64][sch]);
    async16(Bt + (size_t)(n0 + srow) * K + k0 + sch,           &Bs [srow][sch]);       // srow<64
    async16(Bt + (size_t)(n0 + srow) * K + k0 + 32 + sch,      &Bs2[srow][sch]);
    __syncthreads();
    bf16x8 af[4], bfr[2];
#pragma unroll
    for (int i = 0; i < 4; ++i)
      af[i] = *(const bf16x8*)&As[wm + i * 16 + l16][quad * 8];
#pragma unroll
    for (int i = 0; i < 2; ++i)
      bfr[i] = *(const bf16x8*)&Bs[wn + i * 16 + l16][quad * 8];
#pragma unroll
    for (int mi = 0; mi < 4; ++mi)
#pragma unroll
      for (int ni = 0; ni < 2; ++ni)
        acc[mi][ni] = __builtin_amdgcn_mfma_f32_16x16x32_bf16(af[mi], bfr[ni], acc[mi][ni], 0, 0, 0);
#pragma unroll
    for (int i = 0; i < 4; ++i)
      af[i] = *(const bf16x8*)&As2[wm + i * 16 + l16][quad * 8];
#pragma unroll
    for (int i = 0; i < 2; ++i)
      bfr[i] = *(const bf16x8*)&Bs2[wn + i * 16 + l16][quad * 8];
#pragma unroll
    for (int mi = 0; mi < 4; ++mi)
#pragma unroll
      for (int ni = 0; ni < 2; ++ni)
        acc[mi][ni] = __builtin_amdgcn_mfma_f32_16x16x32_bf16(af[mi], bfr[ni], acc[mi][ni], 0, 0, 0);
  }
#pragma unroll
  for (int mi = 0; mi < 4; ++mi)
#pragma unroll
    for (int ni = 0; ni < 2; ++ni) {
      const int col = n0 + wn + ni * 16 + l16;
      const float bv = bias[col];
      const int row0 = m0 + wm + mi * 16 + quad * 4;
#pragma unroll
      for (int r = 0; r < 4; ++r)
        C[(size_t)(row0 + r) * N + col] = acc[mi][ni][r] + bv;
    }
}

// ------- causal flash attention R23: R22 + setprio + 2x unroll -------
// R22 confirmed issue-bound at 4 waves/SIMD (~370-400 issue-cyc/wave-tile;
// accounting closes vs 106K measured cyc). R23 shaves issue:
//  - s_setprio(1) around QK and PV MFMA clusters (T5: +4-7% measured on
//    attn-shaped kernels with independent blocks per CU; null only on
//    lockstep GEMM)
//  - t-loop unrolled 2x with COMPILE-TIME buffer index: kills per-tile cur
//    selects; all 16 KV read addrs + STAGE dests fold to static offsets.
// Everything else identical to R22 (split-Q, K+V LDS dbuf 40960B = 4/CU,
// swizzled staging, no-max exp2 softmax, no merge tree).
__global__ __launch_bounds__(256) void attn_kernel(
    const unsigned short* __restrict__ Qh, const unsigned short* __restrict__ Kh,
    const unsigned short* __restrict__ Vt, unsigned short* __restrict__ ctx) {
  const int id = blockIdx.x;                  // 1024 blocks
  const int j = id >> 3;                      // 0..127
  const int bh = (id & 7) | ((j & 3) << 3);   // id%8 constant per bh -> XCD-local
  const int s = 31 - (j >> 2);                // 64-query strip, long strips first
  const int b = bh >> 4, h = bh & 15;
  const int tid = threadIdx.x;
  const int wave = tid >> 6, lane = tid & 63;
  const int quad = lane >> 4, l16 = lane & 15;
  const int q0 = s * 64;
  const int T = s + 1;                        // 64-key tiles (causal)

  // KV[buf][row][col]: rows 0-63 = K keys, 64-127 = V d-rows; 128B rows,
  // XOR-swizzled (byte col ^= (row&7)<<4). Pt: unpadded, XOR-swizzled.
  __shared__ unsigned short KV[2][128][64];   // 32768 B
  __shared__ unsigned short Pt[4][16][64];    //  8192 B  (total 40960 = 4/CU)

  const unsigned short* Qp = Qh + (size_t)bh * 2048 * 64;
  const unsigned short* Kg = Kh + (size_t)bh * 2048 * 64;
  const unsigned short* Vg = Vt + (size_t)bh * 64 * 2048;  // 32-key tile t2 at +t2*2048

  // hoisted STAGE addressing (rule #21: linear LDS dest, inverse-swizzled
  // global source). All sources advance 4096 elems/tile.
  const int swzc = ((tid & 7) * 16) ^ (((tid >> 3) & 7) << 4);  // byte col
  const int r32 = tid >> 3;                   // row within 32-row group
  const unsigned short* gK0 = Kg + (size_t)r32 * 64 + (swzc >> 1);
  const unsigned short* gK1 = gK0 + 32 * 64;
  const int vkey = swzc >> 1;
  const unsigned short* gV0 = Vg + (size_t)(vkey >> 5) * 2048 + r32 * 32 + (vkey & 31);
  const unsigned short* gV1 = gV0 + 32 * 32;  // d += 32
  unsigned short* lb0 = &KV[0][0][0] + tid * 8;
  unsigned short* lb1 = &KV[1][0][0] + tid * 8;

#define STAGE(bf_, t_)                                      \
  do {                                                      \
    const size_t toff = (size_t)(t_) * 4096;                \
    unsigned short* lb = (bf_) ? lb1 : lb0;                 \
    async16(gK0 + toff, lb);                                \
    async16(gK1 + toff, lb + 2048);                         \
    async16(gV0 + toff, lb + 4096);                         \
    async16(gV1 + toff, lb + 6144);                         \
  } while (0)

  // Q fragments: 16 queries per wave, B-frag n=query(l16), k=dim(quad*8+jj)
  bf16x8 qf[2];
#pragma unroll
  for (int kk = 0; kk < 2; ++kk)
    qf[kk] = *(const bf16x8*)(Qp + (size_t)(q0 + wave * 16 + l16) * 64 + kk * 32 + quad * 8);

  bf16x8 ones;  // A-frag of 1.0: l-row = 1^T P
#pragma unroll
  for (int jj = 0; jj < 8; ++jj) ones[jj] = (short)0x3F80;

  f32x4 o[5] = {};                    // [0..3]=O^T dg blocks, [4]=l row

  const int psw = (l16 & 7) << 3;     // Pt element-col swizzle for this lane

// one 64-key tile with COMPILE-TIME buffer index CUR
#define ATTN_TILE(CUR, t_)                                                      \
  {                                                                             \
    const int k0 = (t_) * 64;                                                   \
    __syncthreads();                  /* staged tile t_ visible */              \
    if ((t_) + 1 < T) STAGE(CUR ^ 1, (t_) + 1);  /* in flight during compute */ \
    f32x4 st[4] = {};                                                           \
    __builtin_amdgcn_s_setprio(1);                                              \
    _Pragma("unroll")                                                           \
    for (int keyg = 0; keyg < 4; ++keyg) {                                      \
      _Pragma("unroll")                                                         \
      for (int kk = 0; kk < 2; ++kk) {                                          \
        const int r = keyg * 16 + l16;                                          \
        const int cp = (kk * 64 + quad * 16) ^ ((r & 7) << 4);                  \
        bf16x8 kf = *(const bf16x8*)&KV[CUR][r][cp >> 1];                       \
        st[keyg] = __builtin_amdgcn_mfma_f32_16x16x32_bf16(kf, qf[kk], st[keyg], 0, 0, 0); \
      }                                                                         \
    }                                                                           \
    __builtin_amdgcn_s_setprio(0);                                              \
    bf16x8 vf[4][2];                                                            \
    _Pragma("unroll")                                                           \
    for (int dg = 0; dg < 4; ++dg) {                                            \
      _Pragma("unroll")                                                         \
      for (int half = 0; half < 2; ++half) {                                    \
        const int row = 64 + dg * 16 + l16;                                     \
        const int cp = (half * 64 + quad * 16) ^ ((row & 7) << 4);              \
        vf[dg][half] = *(const bf16x8*)&KV[CUR][row][cp >> 1];                  \
      }                                                                         \
    }                                                                           \
    if ((t_) == T - 1) { /* causal mask: diagonal tile only */                  \
      _Pragma("unroll")                                                         \
      for (int keyg = 0; keyg < 4; ++keyg) {                                    \
        _Pragma("unroll")                                                       \
        for (int r = 0; r < 4; ++r) {                                           \
          const int key = k0 + keyg * 16 + quad * 4 + r;                        \
          if (key > q0 + wave * 16 + l16) st[keyg][r] = -INFINITY;              \
        }                                                                       \
      }                                                                         \
    }                                                                           \
    _Pragma("unroll")                                                           \
    for (int keyg = 0; keyg < 4; ++keyg) {                                      \
      float p0 = exp2f(st[keyg][0]);                                            \
      float p1 = exp2f(st[keyg][1]);                                            \
      float p2 = exp2f(st[keyg][2]);                                            \
      float p3 = exp2f(st[keyg][3]);                                            \
      uint2 pk;  /* truncate-to-bf16 pack via v_perm */                         \
      pk.x = __builtin_amdgcn_perm(fb(p1), fb(p0), 0x07060302u);                \
      pk.y = __builtin_amdgcn_perm(fb(p3), fb(p2), 0x07060302u);                \
      *(uint2*)&Pt[wave][l16][(keyg * 16 + quad * 4) ^ psw] = pk;               \
    }                                                                           \
    bf16x8 pb[2];                                                               \
    _Pragma("unroll")                                                           \
    for (int half = 0; half < 2; ++half)                                        \
      pb[half] = *(const bf16x8*)&Pt[wave][l16][(half * 32 + quad * 8) ^ psw];  \
    __builtin_amdgcn_s_setprio(1);                                              \
    _Pragma("unroll")                                                           \
    for (int dg = 0; dg < 4; ++dg) {                                            \
      o[dg] = __builtin_amdgcn_mfma_f32_16x16x32_bf16(vf[dg][0], pb[0], o[dg], 0, 0, 0); \
      o[dg] = __builtin_amdgcn_mfma_f32_16x16x32_bf16(vf[dg][1], pb[1], o[dg], 0, 0, 0); \
    }                                                                           \
    o[4] = __builtin_amdgcn_mfma_f32_16x16x32_bf16(ones, pb[0], o[4], 0, 0, 0); \
    o[4] = __builtin_amdgcn_mfma_f32_16x16x32_bf16(ones, pb[1], o[4], 0, 0, 0); \
    __builtin_amdgcn_s_setprio(0);                                              \
  }

  STAGE(0, 0);
  for (int t = 0; t < T; t += 2) {
    ATTN_TILE(0, t);
    if (t + 1 < T) ATTN_TILE(1, t + 1);
  }
#undef ATTN_TILE
#undef STAGE

  // ---- epilogue: no merge — wave owns its 16 queries entirely ----
  const float inv = 1.f / o[4][0];
  const size_t base = (size_t)(b * 2048 + q0 + wave * 16 + l16) * 1024 + h * 64;
#pragma unroll
  for (int dg = 0; dg < 4; ++dg) {
    ushort4 us;
    us.x = f2bf(o[dg][0] * inv); us.y = f2bf(o[dg][1] * inv);
    us.z = f2bf(o[dg][2] * inv); us.w = f2bf(o[dg][3] * inv);
    *(ushort4*)&ctx[base + dg * 16 + quad * 4] = us;
  }
}

// ---------------- launch ----------------
extern "C" void kernel_launch(void* const* d_in, const int* in_sizes, int n_in,
                              void* d_out, int out_size, void* d_ws, size_t ws_size,
                              hipStream_t stream) {
  const float* x  = (const float*)d_in[0];
  const float* Wq = (const float*)d_in[1];
  const float* Wk = (const float*)d_in[2];
  const float* Wv = (const float*)d_in[3];
  const float* Wo = (const float*)d_in[4];
  const float* bo = (const float*)d_in[5];
  float* out = (float*)d_out;

  // workspace layout (48 MB total)
  char* ws = (char*)d_ws;
  unsigned short* Xb    = (unsigned short*)(ws);                          //  8 MB [4096][1024]
  unsigned short* Wqkvt = (unsigned short*)(ws + (size_t)8  * 1048576);   //  6 MB [3072][1024]
  unsigned short* Wot   = (unsigned short*)(ws + (size_t)14 * 1048576);   //  2 MB [1024][1024]
  unsigned short* Qhb   = (unsigned short*)(ws + (size_t)16 * 1048576);   //  8 MB [32][2048][64]
  unsigned short* Khb   = (unsigned short*)(ws + (size_t)24 * 1048576);   //  8 MB [32][2048][64]
  unsigned short* Vtb   = (unsigned short*)(ws + (size_t)32 * 1048576);   //  8 MB [32][64][64][32]
  unsigned short* CT    = (unsigned short*)(ws + (size_t)40 * 1048576);   //  8 MB [4096][1024]

  prep_kernel<<<dim3(32, 32, 5), 256, 0, stream>>>(x, Wq, Wk, Wv, Wo, Xb, Wqkvt, Wot);
  gemm_qkv<<<768, 256, 0, stream>>>(Xb, Wqkvt, Qhb, Khb, Vtb, 1024);
  attn_kernel<<<1024, 256, 0, stream>>>(Qhb, Khb, Vtb, CT);
  gemm_out<<<512, 256, 0, stream>>>(CT, Wot, out, bo, 1024, 1024);
}

// Round 13
// 164.292 us; speedup vs baseline: 1.1677x; 1.0166x over previous
//
#include <hip/hip_runtime.h>
#include <hip/hip_bf16.h>
#include <math.h>

typedef __attribute__((ext_vector_type(8))) short bf16x8;
typedef __attribute__((ext_vector_type(8))) unsigned short u16x8;
typedef __attribute__((ext_vector_type(4))) float f32x4;

__device__ __forceinline__ unsigned short f2bf(float f) {
  union { float f; unsigned u; } c; c.f = f;
  unsigned u = c.u;
  u += 0x7fffu + ((u >> 16) & 1u);   // round-to-nearest-even
  return (unsigned short)(u >> 16);
}
__device__ __forceinline__ unsigned fb(float x) {
  union { float f; unsigned u; } c; c.f = x; return c.u;
}
// raw hardware exp2: ONE v_exp_f32, no libm guard code (guard only matters
// for denormal-range results; scores bounded, -inf -> 0 is exact).
#if __has_builtin(__builtin_amdgcn_exp2f)
__device__ __forceinline__ float fexp2(float x) { return __builtin_amdgcn_exp2f(x); }
#else
__device__ __forceinline__ float fexp2(float x) {
  float r;
  asm volatile("v_exp_f32 %0, %1" : "=v"(r) : "v"(x));
  return r;
}
#endif
// async global->LDS, 16B per lane; LDS dest must be wave-uniform base + lane*16
__device__ __forceinline__ void async16(const unsigned short* g, unsigned short* l) {
  __builtin_amdgcn_global_load_lds(
      (const __attribute__((address_space(1))) unsigned int*)g,
      (__attribute__((address_space(3))) unsigned int*)l, 16, 0, 0);
}

// -------- fused prep: z<4 transpose+cast weights (z=0 Wq scaled by C); z=4 cast x --------
__global__ __launch_bounds__(256) void prep_kernel(
    const float* __restrict__ x, const float* __restrict__ Wq,
    const float* __restrict__ Wk, const float* __restrict__ Wv,
    const float* __restrict__ Wo, unsigned short* __restrict__ Xb,
    unsigned short* __restrict__ Wqkvt, unsigned short* __restrict__ Wot) {
  const int z = blockIdx.z;
  if (z == 4) {  // cast x: 1M float4 over 1024 blocks, 4 float4/thread
    const int bid = blockIdx.y * 32 + blockIdx.x;
#pragma unroll
    for (int i = 0; i < 4; ++i) {
      const int idx = (bid * 4 + i) * 256 + threadIdx.x;
      float4 v = ((const float4*)x)[idx];
      ushort4 o;
      o.x = f2bf(v.x); o.y = f2bf(v.y); o.z = f2bf(v.z); o.w = f2bf(v.w);
      ((ushort4*)Xb)[idx] = o;
    }
    return;
  }
  __shared__ float t[32][33];
  const float* src = (z == 0) ? Wq : (z == 1) ? Wk : (z == 2) ? Wv : Wo;
  unsigned short* dst = (z < 3) ? (Wqkvt + (size_t)z * 1024 * 1024) : Wot;
  const float scale = (z == 0) ? 0.18033688f : 1.0f;  // log2(e)/sqrt(64) into Wq
  int tx = threadIdx.x & 31, ty = threadIdx.x >> 5;
  int bx = blockIdx.x, by = blockIdx.y;
#pragma unroll
  for (int i = 0; i < 4; ++i)
    t[ty + i * 8][tx] = src[(size_t)(by * 32 + ty + i * 8) * 1024 + bx * 32 + tx];
  __syncthreads();
#pragma unroll
  for (int i = 0; i < 4; ++i)
    dst[(size_t)(bx * 32 + ty + i * 8) * 1024 + by * 32 + tx] = f2bf(t[tx][ty + i * 8] * scale);
}

// ---------------- QKV GEMM: 128x128 tile, BK=64, XCD-swizzled ----------------
// (epilogue = exact R11 form; Q-scale lives in the weights now)
__global__ __launch_bounds__(256) void gemm_qkv(
    const unsigned short* __restrict__ A, const unsigned short* __restrict__ Bt,
    unsigned short* __restrict__ Qh, unsigned short* __restrict__ Kh,
    unsigned short* __restrict__ Vt, int K) {
  __shared__ unsigned short As [128][32];  // unpadded: global_load_lds lane ordering
  __shared__ unsigned short As2[128][32];
  __shared__ unsigned short Bs [128][32];
  __shared__ unsigned short Bs2[128][32];
  const int flat = blockIdx.x;
  const int xcd = flat & 7, idx = flat >> 3;      // 96 blocks per XCD
  const int mg = xcd >> 1, ng = xcd & 1;          // 4x2 XCD rectangle grid
  const int m0 = (mg * 8 + (idx & 7)) * 128;      // 32 m-tiles
  const int n0 = (ng * 12 + (idx >> 3)) * 128;    // 24 n-tiles
  const int tid = threadIdx.x;
  const int wave = tid >> 6, lane = tid & 63;
  const int quad = lane >> 4, l16 = lane & 15;
  const int wm = (wave >> 1) * 64, wn = (wave & 1) * 64;
  const int srow = tid >> 2, sch = (tid & 3) * 8;  // LDS byte addr = tid*16
  f32x4 acc[4][4] = {};

  for (int k0 = 0; k0 < K; k0 += 64) {
    __syncthreads();
    async16(A  + (size_t)(m0 + srow) * K + k0 + sch,           &As [srow][sch]);
    async16(A  + (size_t)(m0 + srow + 64) * K + k0 + sch,      &As [srow + 64][sch]);
    async16(A  + (size_t)(m0 + srow) * K + k0 + 32 + sch,      &As2[srow][sch]);
    async16(A  + (size_t)(m0 + srow + 64) * K + k0 + 32 + sch, &As2[srow + 64][sch]);
    async16(Bt + (size_t)(n0 + srow) * K + k0 + sch,           &Bs [srow][sch]);
    async16(Bt + (size_t)(n0 + srow + 64) * K + k0 + sch,      &Bs [srow + 64][sch]);
    async16(Bt + (size_t)(n0 + srow) * K + k0 + 32 + sch,      &Bs2[srow][sch]);
    async16(Bt + (size_t)(n0 + srow + 64) * K + k0 + 32 + sch, &Bs2[srow + 64][sch]);
    __syncthreads();
    bf16x8 af[4], bfr[4];
#pragma unroll
    for (int i = 0; i < 4; ++i) {
      af[i]  = *(const bf16x8*)&As[wm + i * 16 + l16][quad * 8];
      bfr[i] = *(const bf16x8*)&Bs[wn + i * 16 + l16][quad * 8];
    }
#pragma unroll
    for (int mi = 0; mi < 4; ++mi)
#pragma unroll
      for (int ni = 0; ni < 4; ++ni)
        acc[mi][ni] = __builtin_amdgcn_mfma_f32_16x16x32_bf16(af[mi], bfr[ni], acc[mi][ni], 0, 0, 0);
#pragma unroll
    for (int i = 0; i < 4; ++i) {
      af[i]  = *(const bf16x8*)&As2[wm + i * 16 + l16][quad * 8];
      bfr[i] = *(const bf16x8*)&Bs2[wn + i * 16 + l16][quad * 8];
    }
#pragma unroll
    for (int mi = 0; mi < 4; ++mi)
#pragma unroll
      for (int ni = 0; ni < 4; ++ni)
        acc[mi][ni] = __builtin_amdgcn_mfma_f32_16x16x32_bf16(af[mi], bfr[ni], acc[mi][ni], 0, 0, 0);
  }

#pragma unroll
  for (int mi = 0; mi < 4; ++mi) {
#pragma unroll
    for (int ni = 0; ni < 4; ++ni) {
      const int col = n0 + wn + ni * 16 + l16;
      const int token0 = m0 + wm + mi * 16 + quad * 4;
      const int bb = token0 >> 11, s0 = token0 & 2047;
      if (col < 2048) {  // Q or K, head-major [bh][s][64]
        const int hh = (col & 1023) >> 6, d = col & 63;
        unsigned short* dst = (col < 1024) ? Qh : Kh;
        dst += ((size_t)(bb * 16 + hh) * 2048 + s0) * 64 + d;
#pragma unroll
        for (int r = 0; r < 4; ++r) dst[(size_t)r * 64] = f2bf(acc[mi][ni][r]);
      } else {           // V, tiled [bh][s>>5][d][32]
        const int vc = col - 2048, hh = vc >> 6, d = vc & 63;
        ushort4 us;
        us.x = f2bf(acc[mi][ni][0]); us.y = f2bf(acc[mi][ni][1]);
        us.z = f2bf(acc[mi][ni][2]); us.w = f2bf(acc[mi][ni][3]);
        *(ushort4*)&Vt[(((size_t)(bb * 16 + hh) * 64 + (s0 >> 5)) * 64 + d) * 32 + (s0 & 31)] = us;
      }
    }
  }
}

// ---------------- output GEMM: 128x64 tile, BK=64, XCD-swizzled ----------------
__global__ __launch_bounds__(256) void gemm_out(
    const unsigned short* __restrict__ A, const unsigned short* __restrict__ Bt,
    float* __restrict__ C, const float* __restrict__ bias, int N, int K) {
  __shared__ unsigned short As [128][32];
  __shared__ unsigned short As2[128][32];
  __shared__ unsigned short Bs [64][32];
  __shared__ unsigned short Bs2[64][32];
  const int flat = blockIdx.x;
  const int xcd = flat & 7, idx = flat >> 3;      // 64 blocks per XCD
  const int mg = xcd >> 1, ng = xcd & 1;
  const int m0 = (mg * 8 + (idx & 7)) * 128;      // 32 m-tiles
  const int n0 = (ng * 8 + (idx >> 3)) * 64;      // 16 n-tiles
  const int tid = threadIdx.x;
  const int wave = tid >> 6, lane = tid & 63;
  const int quad = lane >> 4, l16 = lane & 15;
  const int wm = (wave >> 1) * 64, wn = (wave & 1) * 32;
  const int srow = tid >> 2, sch = (tid & 3) * 8;
  f32x4 acc[4][2] = {};

  for (int k0 = 0; k0 < K; k0 += 64) {
    __syncthreads();
    async16(A  + (size_t)(m0 + srow) * K + k0 + sch,           &As [srow][sch]);
    async16(A  + (size_t)(m0 + srow + 64) * K + k0 + sch,      &As [srow + 64][sch]);
    async16(A  + (size_t)(m0 + srow) * K + k0 + 32 + sch,      &As2[srow][sch]);
    async16(A  + (size_t)(m0 + srow + 64) * K + k0 + 32 + sch, &As2[srow + 64][sch]);
    async16(Bt + (size_t)(n0 + srow) * K + k0 + sch,           &Bs [srow][sch]);       // srow<64
    async16(Bt + (size_t)(n0 + srow) * K + k0 + 32 + sch,      &Bs2[srow][sch]);
    __syncthreads();
    bf16x8 af[4], bfr[2];
#pragma unroll
    for (int i = 0; i < 4; ++i)
      af[i] = *(const bf16x8*)&As[wm + i * 16 + l16][quad * 8];
#pragma unroll
    for (int i = 0; i < 2; ++i)
      bfr[i] = *(const bf16x8*)&Bs[wn + i * 16 + l16][quad * 8];
#pragma unroll
    for (int mi = 0; mi < 4; ++mi)
#pragma unroll
      for (int ni = 0; ni < 2; ++ni)
        acc[mi][ni] = __builtin_amdgcn_mfma_f32_16x16x32_bf16(af[mi], bfr[ni], acc[mi][ni], 0, 0, 0);
#pragma unroll
    for (int i = 0; i < 4; ++i)
      af[i] = *(const bf16x8*)&As2[wm + i * 16 + l16][quad * 8];
#pragma unroll
    for (int i = 0; i < 2; ++i)
      bfr[i] = *(const bf16x8*)&Bs2[wn + i * 16 + l16][quad * 8];
#pragma unroll
    for (int mi = 0; mi < 4; ++mi)
#pragma unroll
      for (int ni = 0; ni < 2; ++ni)
        acc[mi][ni] = __builtin_amdgcn_mfma_f32_16x16x32_bf16(af[mi], bfr[ni], acc[mi][ni], 0, 0, 0);
  }
#pragma unroll
  for (int mi = 0; mi < 4; ++mi)
#pragma unroll
    for (int ni = 0; ni < 2; ++ni) {
      const int col = n0 + wn + ni * 16 + l16;
      const float bv = bias[col];
      const int row0 = m0 + wm + mi * 16 + quad * 4;
#pragma unroll
      for (int r = 0; r < 4; ++r)
        C[(size_t)(row0 + r) * N + col] = acc[mi][ni][r] + bv;
    }
}

// ------- causal flash attention R25 (= R24 resubmit; R24 was an infra flake,
// kernel never executed): R23 + RAW v_exp_f32 -------
// R23 post-mortem: VALUBusy 46% = ~90 VALU instrs/wave-tile, ~2.5x the
// written code. Culprit: libm exp2f (no -ffast-math) = guarded
// __ocml_exp2_f32: range check + TWO v_exp_f32 + cndmask + fixup (~5-6
// instrs/call x 16 calls/tile). Raw v_exp_f32 is exact for our range
// (|s| << 126; -inf -> 0 exactly; denormal-flush invisible at bf16).
// Everything else identical to R23 (split-Q, K+V LDS dbuf 40960B = 4/CU,
// setprio, 2x unroll, swizzled staging, no merge tree).
__global__ __launch_bounds__(256) void attn_kernel(
    const unsigned short* __restrict__ Qh, const unsigned short* __restrict__ Kh,
    const unsigned short* __restrict__ Vt, unsigned short* __restrict__ ctx) {
  const int id = blockIdx.x;                  // 1024 blocks
  const int j = id >> 3;                      // 0..127
  const int bh = (id & 7) | ((j & 3) << 3);   // id%8 constant per bh -> XCD-local
  const int s = 31 - (j >> 2);                // 64-query strip, long strips first
  const int b = bh >> 4, h = bh & 15;
  const int tid = threadIdx.x;
  const int wave = tid >> 6, lane = tid & 63;
  const int quad = lane >> 4, l16 = lane & 15;
  const int q0 = s * 64;
  const int T = s + 1;                        // 64-key tiles (causal)

  // KV[buf][row][col]: rows 0-63 = K keys, 64-127 = V d-rows; 128B rows,
  // XOR-swizzled (byte col ^= (row&7)<<4). Pt: unpadded, XOR-swizzled.
  __shared__ unsigned short KV[2][128][64];   // 32768 B
  __shared__ unsigned short Pt[4][16][64];    //  8192 B  (total 40960 = 4/CU)

  const unsigned short* Qp = Qh + (size_t)bh * 2048 * 64;
  const unsigned short* Kg = Kh + (size_t)bh * 2048 * 64;
  const unsigned short* Vg = Vt + (size_t)bh * 64 * 2048;  // 32-key tile t2 at +t2*2048

  // hoisted STAGE addressing (rule #21: linear LDS dest, inverse-swizzled
  // global source). All sources advance 4096 elems/tile.
  const int swzc = ((tid & 7) * 16) ^ (((tid >> 3) & 7) << 4);  // byte col
  const int r32 = tid >> 3;                   // row within 32-row group
  const unsigned short* gK0 = Kg + (size_t)r32 * 64 + (swzc >> 1);
  const unsigned short* gK1 = gK0 + 32 * 64;
  const int vkey = swzc >> 1;
  const unsigned short* gV0 = Vg + (size_t)(vkey >> 5) * 2048 + r32 * 32 + (vkey & 31);
  const unsigned short* gV1 = gV0 + 32 * 32;  // d += 32
  unsigned short* lb0 = &KV[0][0][0] + tid * 8;
  unsigned short* lb1 = &KV[1][0][0] + tid * 8;

#define STAGE(bf_, t_)                                      \
  do {                                                      \
    const size_t toff = (size_t)(t_) * 4096;                \
    unsigned short* lb = (bf_) ? lb1 : lb0;                 \
    async16(gK0 + toff, lb);                                \
    async16(gK1 + toff, lb + 2048);                         \
    async16(gV0 + toff, lb + 4096);                         \
    async16(gV1 + toff, lb + 6144);                         \
  } while (0)

  // Q fragments: 16 queries per wave, B-frag n=query(l16), k=dim(quad*8+jj)
  bf16x8 qf[2];
#pragma unroll
  for (int kk = 0; kk < 2; ++kk)
    qf[kk] = *(const bf16x8*)(Qp + (size_t)(q0 + wave * 16 + l16) * 64 + kk * 32 + quad * 8);

  bf16x8 ones;  // A-frag of 1.0: l-row = 1^T P
#pragma unroll
  for (int jj = 0; jj < 8; ++jj) ones[jj] = (short)0x3F80;

  f32x4 o[5] = {};                    // [0..3]=O^T dg blocks, [4]=l row

  const int psw = (l16 & 7) << 3;     // Pt element-col swizzle for this lane

// one 64-key tile with COMPILE-TIME buffer index CUR
#define ATTN_TILE(CUR, t_)                                                      \
  {                                                                             \
    const int k0 = (t_) * 64;                                                   \
    __syncthreads();                  /* staged tile t_ visible */              \
    if ((t_) + 1 < T) STAGE(CUR ^ 1, (t_) + 1);  /* in flight during compute */ \
    f32x4 st[4] = {};                                                           \
    __builtin_amdgcn_s_setprio(1);                                              \
    _Pragma("unroll")                                                           \
    for (int keyg = 0; keyg < 4; ++keyg) {                                      \
      _Pragma("unroll")                                                         \
      for (int kk = 0; kk < 2; ++kk) {                                          \
        const int r = keyg * 16 + l16;                                          \
        const int cp = (kk * 64 + quad * 16) ^ ((r & 7) << 4);                  \
        bf16x8 kf = *(const bf16x8*)&KV[CUR][r][cp >> 1];                       \
        st[keyg] = __builtin_amdgcn_mfma_f32_16x16x32_bf16(kf, qf[kk], st[keyg], 0, 0, 0); \
      }                                                                         \
    }                                                                           \
    __builtin_amdgcn_s_setprio(0);                                              \
    bf16x8 vf[4][2];                                                            \
    _Pragma("unroll")                                                           \
    for (int dg = 0; dg < 4; ++dg) {                                            \
      _Pragma("unroll")                                                         \
      for (int half = 0; half < 2; ++half) {                                    \
        const int row = 64 + dg * 16 + l16;                                     \
        const int cp = (half * 64 + quad * 16) ^ ((row & 7) << 4);              \
        vf[dg][half] = *(const bf16x8*)&KV[CUR][row][cp >> 1];                  \
      }                                                                         \
    }                                                                           \
    if ((t_) == T - 1) { /* causal mask: diagonal tile only */                  \
      _Pragma("unroll")                                                         \
      for (int keyg = 0; keyg < 4; ++keyg) {                                    \
        _Pragma("unroll")                                                       \
        for (int r = 0; r < 4; ++r) {                                           \
          const int key = k0 + keyg * 16 + quad * 4 + r;                        \
          if (key > q0 + wave * 16 + l16) st[keyg][r] = -INFINITY;              \
        }                                                                       \
      }                                                                         \
    }                                                                           \
    _Pragma("unroll")                                                           \
    for (int keyg = 0; keyg < 4; ++keyg) {                                      \
      float p0 = fexp2(st[keyg][0]);                                            \
      float p1 = fexp2(st[keyg][1]);                                            \
      float p2 = fexp2(st[keyg][2]);                                            \
      float p3 = fexp2(st[keyg][3]);                                            \
      uint2 pk;  /* truncate-to-bf16 pack via v_perm */                         \
      pk.x = __builtin_amdgcn_perm(fb(p1), fb(p0), 0x07060302u);                \
      pk.y = __builtin_amdgcn_perm(fb(p3), fb(p2), 0x07060302u);                \
      *(uint2*)&Pt[wave][l16][(keyg * 16 + quad * 4) ^ psw] = pk;               \
    }                                                                           \
    bf16x8 pb[2];                                                               \
    _Pragma("unroll")                                                           \
    for (int half = 0; half < 2; ++half)                                        \
      pb[half] = *(const bf16x8*)&Pt[wave][l16][(half * 32 + quad * 8) ^ psw];  \
    __builtin_amdgcn_s_setprio(1);                                              \
    _Pragma("unroll")                                                           \
    for (int dg = 0; dg < 4; ++dg) {                                            \
      o[dg] = __builtin_amdgcn_mfma_f32_16x16x32_bf16(vf[dg][0], pb[0], o[dg], 0, 0, 0); \
      o[dg] = __builtin_amdgcn_mfma_f32_16x16x32_bf16(vf[dg][1], pb[1], o[dg], 0, 0, 0); \
    }                                                                           \
    o[4] = __builtin_amdgcn_mfma_f32_16x16x32_bf16(ones, pb[0], o[4], 0, 0, 0); \
    o[4] = __builtin_amdgcn_mfma_f32_16x16x32_bf16(ones, pb[1], o[4], 0, 0, 0); \
    __builtin_amdgcn_s_setprio(0);                                              \
  }

  STAGE(0, 0);
  for (int t = 0; t < T; t += 2) {
    ATTN_TILE(0, t);
    if (t + 1 < T) ATTN_TILE(1, t + 1);
  }
#undef ATTN_TILE
#undef STAGE

  // ---- epilogue: no merge — wave owns its 16 queries entirely ----
  const float inv = 1.f / o[4][0];
  const size_t base = (size_t)(b * 2048 + q0 + wave * 16 + l16) * 1024 + h * 64;
#pragma unroll
  for (int dg = 0; dg < 4; ++dg) {
    ushort4 us;
    us.x = f2bf(o[dg][0] * inv); us.y = f2bf(o[dg][1] * inv);
    us.z = f2bf(o[dg][2] * inv); us.w = f2bf(o[dg][3] * inv);
    *(ushort4*)&ctx[base + dg * 16 + quad * 4] = us;
  }
}

// ---------------- launch ----------------
extern "C" void kernel_launch(void* const* d_in, const int* in_sizes, int n_in,
                              void* d_out, int out_size, void* d_ws, size_t ws_size,
                              hipStream_t stream) {
  const float* x  = (const float*)d_in[0];
  const float* Wq = (const float*)d_in[1];
  const float* Wk = (const float*)d_in[2];
  const float* Wv = (const float*)d_in[3];
  const float* Wo = (const float*)d_in[4];
  const float* bo = (const float*)d_in[5];
  float* out = (float*)d_out;

  // workspace layout (48 MB total)
  char* ws = (char*)d_ws;
  unsigned short* Xb    = (unsigned short*)(ws);                          //  8 MB [4096][1024]
  unsigned short* Wqkvt = (unsigned short*)(ws + (size_t)8  * 1048576);   //  6 MB [3072][1024]
  unsigned short* Wot   = (unsigned short*)(ws + (size_t)14 * 1048576);   //  2 MB [1024][1024]
  unsigned short* Qhb   = (unsigned short*)(ws + (size_t)16 * 1048576);   //  8 MB [32][2048][64]
  unsigned short* Khb   = (unsigned short*)(ws + (size_t)24 * 1048576);   //  8 MB [32][2048][64]
  unsigned short* Vtb   = (unsigned short*)(ws + (size_t)32 * 1048576);   //  8 MB [32][64][64][32]
  unsigned short* CT    = (unsigned short*)(ws + (size_t)40 * 1048576);   //  8 MB [4096][1024]

  prep_kernel<<<dim3(32, 32, 5), 256, 0, stream>>>(x, Wq, Wk, Wv, Wo, Xb, Wqkvt, Wot);
  gemm_qkv<<<768, 256, 0, stream>>>(Xb, Wqkvt, Qhb, Khb, Vtb, 1024);
  attn_kernel<<<1024, 256, 0, stream>>>(Qhb, Khb, Vtb, CT);
  gemm_out<<<512, 256, 0, stream>>>(CT, Wot, out, bo, 1024, 1024);
}

// Round 14
// 161.230 us; speedup vs baseline: 1.1899x; 1.0190x over previous
//
#include <hip/hip_runtime.h>
#include <hip/hip_bf16.h>
#include <math.h>

typedef __attribute__((ext_vector_type(8))) short bf16x8;
typedef __attribute__((ext_vector_type(8))) unsigned short u16x8;
typedef __attribute__((ext_vector_type(4))) float f32x4;

__device__ __forceinline__ unsigned short f2bf(float f) {
  union { float f; unsigned u; } c; c.f = f;
  unsigned u = c.u;
  u += 0x7fffu + ((u >> 16) & 1u);   // round-to-nearest-even
  return (unsigned short)(u >> 16);
}
__device__ __forceinline__ unsigned fb(float x) {
  union { float f; unsigned u; } c; c.f = x; return c.u;
}
// raw hardware exp2: ONE v_exp_f32, no libm guard code (guard only matters
// for denormal-range results; scores bounded, -inf -> 0 is exact).
#if __has_builtin(__builtin_amdgcn_exp2f)
__device__ __forceinline__ float fexp2(float x) { return __builtin_amdgcn_exp2f(x); }
#else
__device__ __forceinline__ float fexp2(float x) {
  float r;
  asm volatile("v_exp_f32 %0, %1" : "=v"(r) : "v"(x));
  return r;
}
#endif
// async global->LDS, 16B per lane; LDS dest must be wave-uniform base + lane*16
__device__ __forceinline__ void async16(const unsigned short* g, unsigned short* l) {
  __builtin_amdgcn_global_load_lds(
      (const __attribute__((address_space(1))) unsigned int*)g,
      (__attribute__((address_space(3))) unsigned int*)l, 16, 0, 0);
}

// -------- fused prep: z<4 transpose+cast weights (z=0 Wq scaled by C); z=4 cast x --------
__global__ __launch_bounds__(256) void prep_kernel(
    const float* __restrict__ x, const float* __restrict__ Wq,
    const float* __restrict__ Wk, const float* __restrict__ Wv,
    const float* __restrict__ Wo, unsigned short* __restrict__ Xb,
    unsigned short* __restrict__ Wqkvt, unsigned short* __restrict__ Wot) {
  const int z = blockIdx.z;
  if (z == 4) {  // cast x: 1M float4 over 1024 blocks, 4 float4/thread
    const int bid = blockIdx.y * 32 + blockIdx.x;
#pragma unroll
    for (int i = 0; i < 4; ++i) {
      const int idx = (bid * 4 + i) * 256 + threadIdx.x;
      float4 v = ((const float4*)x)[idx];
      ushort4 o;
      o.x = f2bf(v.x); o.y = f2bf(v.y); o.z = f2bf(v.z); o.w = f2bf(v.w);
      ((ushort4*)Xb)[idx] = o;
    }
    return;
  }
  __shared__ float t[32][33];
  const float* src = (z == 0) ? Wq : (z == 1) ? Wk : (z == 2) ? Wv : Wo;
  unsigned short* dst = (z < 3) ? (Wqkvt + (size_t)z * 1024 * 1024) : Wot;
  const float scale = (z == 0) ? 0.18033688f : 1.0f;  // log2(e)/sqrt(64) into Wq
  int tx = threadIdx.x & 31, ty = threadIdx.x >> 5;
  int bx = blockIdx.x, by = blockIdx.y;
#pragma unroll
  for (int i = 0; i < 4; ++i)
    t[ty + i * 8][tx] = src[(size_t)(by * 32 + ty + i * 8) * 1024 + bx * 32 + tx];
  __syncthreads();
#pragma unroll
  for (int i = 0; i < 4; ++i)
    dst[(size_t)(bx * 32 + ty + i * 8) * 1024 + by * 32 + tx] = f2bf(t[tx][ty + i * 8] * scale);
}

// ---------------- QKV GEMM: 128x128 tile, BK=64, XCD-swizzled ----------------
// (epilogue = exact R11 form; Q-scale lives in the weights now)
__global__ __launch_bounds__(256) void gemm_qkv(
    const unsigned short* __restrict__ A, const unsigned short* __restrict__ Bt,
    unsigned short* __restrict__ Qh, unsigned short* __restrict__ Kh,
    unsigned short* __restrict__ Vt, int K) {
  __shared__ unsigned short As [128][32];  // unpadded: global_load_lds lane ordering
  __shared__ unsigned short As2[128][32];
  __shared__ unsigned short Bs [128][32];
  __shared__ unsigned short Bs2[128][32];
  const int flat = blockIdx.x;
  const int xcd = flat & 7, idx = flat >> 3;      // 96 blocks per XCD
  const int mg = xcd >> 1, ng = xcd & 1;          // 4x2 XCD rectangle grid
  const int m0 = (mg * 8 + (idx & 7)) * 128;      // 32 m-tiles
  const int n0 = (ng * 12 + (idx >> 3)) * 128;    // 24 n-tiles
  const int tid = threadIdx.x;
  const int wave = tid >> 6, lane = tid & 63;
  const int quad = lane >> 4, l16 = lane & 15;
  const int wm = (wave >> 1) * 64, wn = (wave & 1) * 64;
  const int srow = tid >> 2, sch = (tid & 3) * 8;  // LDS byte addr = tid*16
  f32x4 acc[4][4] = {};

  for (int k0 = 0; k0 < K; k0 += 64) {
    __syncthreads();
    async16(A  + (size_t)(m0 + srow) * K + k0 + sch,           &As [srow][sch]);
    async16(A  + (size_t)(m0 + srow + 64) * K + k0 + sch,      &As [srow + 64][sch]);
    async16(A  + (size_t)(m0 + srow) * K + k0 + 32 + sch,      &As2[srow][sch]);
    async16(A  + (size_t)(m0 + srow + 64) * K + k0 + 32 + sch, &As2[srow + 64][sch]);
    async16(Bt + (size_t)(n0 + srow) * K + k0 + sch,           &Bs [srow][sch]);
    async16(Bt + (size_t)(n0 + srow + 64) * K + k0 + sch,      &Bs [srow + 64][sch]);
    async16(Bt + (size_t)(n0 + srow) * K + k0 + 32 + sch,      &Bs2[srow][sch]);
    async16(Bt + (size_t)(n0 + srow + 64) * K + k0 + 32 + sch, &Bs2[srow + 64][sch]);
    __syncthreads();
    bf16x8 af[4], bfr[4];
#pragma unroll
    for (int i = 0; i < 4; ++i) {
      af[i]  = *(const bf16x8*)&As[wm + i * 16 + l16][quad * 8];
      bfr[i] = *(const bf16x8*)&Bs[wn + i * 16 + l16][quad * 8];
    }
#pragma unroll
    for (int mi = 0; mi < 4; ++mi)
#pragma unroll
      for (int ni = 0; ni < 4; ++ni)
        acc[mi][ni] = __builtin_amdgcn_mfma_f32_16x16x32_bf16(af[mi], bfr[ni], acc[mi][ni], 0, 0, 0);
#pragma unroll
    for (int i = 0; i < 4; ++i) {
      af[i]  = *(const bf16x8*)&As2[wm + i * 16 + l16][quad * 8];
      bfr[i] = *(const bf16x8*)&Bs2[wn + i * 16 + l16][quad * 8];
    }
#pragma unroll
    for (int mi = 0; mi < 4; ++mi)
#pragma unroll
      for (int ni = 0; ni < 4; ++ni)
        acc[mi][ni] = __builtin_amdgcn_mfma_f32_16x16x32_bf16(af[mi], bfr[ni], acc[mi][ni], 0, 0, 0);
  }

#pragma unroll
  for (int mi = 0; mi < 4; ++mi) {
#pragma unroll
    for (int ni = 0; ni < 4; ++ni) {
      const int col = n0 + wn + ni * 16 + l16;
      const int token0 = m0 + wm + mi * 16 + quad * 4;
      const int bb = token0 >> 11, s0 = token0 & 2047;
      if (col < 2048) {  // Q or K, head-major [bh][s][64]
        const int hh = (col & 1023) >> 6, d = col & 63;
        unsigned short* dst = (col < 1024) ? Qh : Kh;
        dst += ((size_t)(bb * 16 + hh) * 2048 + s0) * 64 + d;
#pragma unroll
        for (int r = 0; r < 4; ++r) dst[(size_t)r * 64] = f2bf(acc[mi][ni][r]);
      } else {           // V, tiled [bh][s>>5][d][32]
        const int vc = col - 2048, hh = vc >> 6, d = vc & 63;
        ushort4 us;
        us.x = f2bf(acc[mi][ni][0]); us.y = f2bf(acc[mi][ni][1]);
        us.z = f2bf(acc[mi][ni][2]); us.w = f2bf(acc[mi][ni][3]);
        *(ushort4*)&Vt[(((size_t)(bb * 16 + hh) * 64 + (s0 >> 5)) * 64 + d) * 32 + (s0 & 31)] = us;
      }
    }
  }
}

// ------- output GEMM R26: 128x64 tile, BK=128 (halved barrier count) -------
// gemm_out is grid-capped at 2 blocks/CU (512 blocks) — the m132 BK=128
// regression was an occupancy effect (64KB LDS, 3->2 blocks/CU) which cannot
// apply here: 48KB still allows 3/CU >= the grid cap of 2. Halving the
// barrier count (16->8 iterations) amortizes each vmcnt(0)+barrier drain
// over 2x the MFMA work on the kernel with the worst FLOP/staged-byte.
__global__ __launch_bounds__(256) void gemm_out(
    const unsigned short* __restrict__ A, const unsigned short* __restrict__ Bt,
    float* __restrict__ C, const float* __restrict__ bias, int N, int K) {
  __shared__ unsigned short As[4][128][32];   // 32 KB: k-chunks 0..3
  __shared__ unsigned short Bs[4][64][32];    // 16 KB
  const int flat = blockIdx.x;
  const int xcd = flat & 7, idx = flat >> 3;      // 64 blocks per XCD
  const int mg = xcd >> 1, ng = xcd & 1;
  const int m0 = (mg * 8 + (idx & 7)) * 128;      // 32 m-tiles
  const int n0 = (ng * 8 + (idx >> 3)) * 64;      // 16 n-tiles
  const int tid = threadIdx.x;
  const int wave = tid >> 6, lane = tid & 63;
  const int quad = lane >> 4, l16 = lane & 15;
  const int wm = (wave >> 1) * 64, wn = (wave & 1) * 32;
  const int srow = tid >> 2, sch = (tid & 3) * 8;  // LDS byte addr = tid*16 within each buf
  f32x4 acc[4][2] = {};

  for (int k0 = 0; k0 < K; k0 += 128) {
    __syncthreads();
#pragma unroll
    for (int c = 0; c < 4; ++c) {
      async16(A  + (size_t)(m0 + srow) * K + k0 + c * 32 + sch,      &As[c][srow][sch]);
      async16(A  + (size_t)(m0 + srow + 64) * K + k0 + c * 32 + sch, &As[c][srow + 64][sch]);
      async16(Bt + (size_t)(n0 + srow) * K + k0 + c * 32 + sch,      &Bs[c][srow][sch]);   // srow<64
    }
    __syncthreads();
#pragma unroll
    for (int c = 0; c < 4; ++c) {
      bf16x8 af[4], bfr[2];
#pragma unroll
      for (int i = 0; i < 4; ++i)
        af[i] = *(const bf16x8*)&As[c][wm + i * 16 + l16][quad * 8];
#pragma unroll
      for (int i = 0; i < 2; ++i)
        bfr[i] = *(const bf16x8*)&Bs[c][wn + i * 16 + l16][quad * 8];
#pragma unroll
      for (int mi = 0; mi < 4; ++mi)
#pragma unroll
        for (int ni = 0; ni < 2; ++ni)
          acc[mi][ni] = __builtin_amdgcn_mfma_f32_16x16x32_bf16(af[mi], bfr[ni], acc[mi][ni], 0, 0, 0);
    }
  }
#pragma unroll
  for (int mi = 0; mi < 4; ++mi)
#pragma unroll
    for (int ni = 0; ni < 2; ++ni) {
      const int col = n0 + wn + ni * 16 + l16;
      const float bv = bias[col];
      const int row0 = m0 + wm + mi * 16 + quad * 4;
#pragma unroll
      for (int r = 0; r < 4; ++r)
        C[(size_t)(row0 + r) * N + col] = acc[mi][ni][r] + bv;
    }
}

// ------- causal flash attention (R25, frozen): split-Q, K+V LDS dbuf,
// raw v_exp_f32, setprio, 2x unroll, 40960B LDS = 4 blocks/CU -------
__global__ __launch_bounds__(256) void attn_kernel(
    const unsigned short* __restrict__ Qh, const unsigned short* __restrict__ Kh,
    const unsigned short* __restrict__ Vt, unsigned short* __restrict__ ctx) {
  const int id = blockIdx.x;                  // 1024 blocks
  const int j = id >> 3;                      // 0..127
  const int bh = (id & 7) | ((j & 3) << 3);   // id%8 constant per bh -> XCD-local
  const int s = 31 - (j >> 2);                // 64-query strip, long strips first
  const int b = bh >> 4, h = bh & 15;
  const int tid = threadIdx.x;
  const int wave = tid >> 6, lane = tid & 63;
  const int quad = lane >> 4, l16 = lane & 15;
  const int q0 = s * 64;
  const int T = s + 1;                        // 64-key tiles (causal)

  // KV[buf][row][col]: rows 0-63 = K keys, 64-127 = V d-rows; 128B rows,
  // XOR-swizzled (byte col ^= (row&7)<<4). Pt: unpadded, XOR-swizzled.
  __shared__ unsigned short KV[2][128][64];   // 32768 B
  __shared__ unsigned short Pt[4][16][64];    //  8192 B  (total 40960 = 4/CU)

  const unsigned short* Qp = Qh + (size_t)bh * 2048 * 64;
  const unsigned short* Kg = Kh + (size_t)bh * 2048 * 64;
  const unsigned short* Vg = Vt + (size_t)bh * 64 * 2048;  // 32-key tile t2 at +t2*2048

  // hoisted STAGE addressing (rule #21: linear LDS dest, inverse-swizzled
  // global source). All sources advance 4096 elems/tile.
  const int swzc = ((tid & 7) * 16) ^ (((tid >> 3) & 7) << 4);  // byte col
  const int r32 = tid >> 3;                   // row within 32-row group
  const unsigned short* gK0 = Kg + (size_t)r32 * 64 + (swzc >> 1);
  const unsigned short* gK1 = gK0 + 32 * 64;
  const int vkey = swzc >> 1;
  const unsigned short* gV0 = Vg + (size_t)(vkey >> 5) * 2048 + r32 * 32 + (vkey & 31);
  const unsigned short* gV1 = gV0 + 32 * 32;  // d += 32
  unsigned short* lb0 = &KV[0][0][0] + tid * 8;
  unsigned short* lb1 = &KV[1][0][0] + tid * 8;

#define STAGE(bf_, t_)                                      \
  do {                                                      \
    const size_t toff = (size_t)(t_) * 4096;                \
    unsigned short* lb = (bf_) ? lb1 : lb0;                 \
    async16(gK0 + toff, lb);                                \
    async16(gK1 + toff, lb + 2048);                         \
    async16(gV0 + toff, lb + 4096);                         \
    async16(gV1 + toff, lb + 6144);                         \
  } while (0)

  // Q fragments: 16 queries per wave, B-frag n=query(l16), k=dim(quad*8+jj)
  bf16x8 qf[2];
#pragma unroll
  for (int kk = 0; kk < 2; ++kk)
    qf[kk] = *(const bf16x8*)(Qp + (size_t)(q0 + wave * 16 + l16) * 64 + kk * 32 + quad * 8);

  bf16x8 ones;  // A-frag of 1.0: l-row = 1^T P
#pragma unroll
  for (int jj = 0; jj < 8; ++jj) ones[jj] = (short)0x3F80;

  f32x4 o[5] = {};                    // [0..3]=O^T dg blocks, [4]=l row

  const int psw = (l16 & 7) << 3;     // Pt element-col swizzle for this lane

// one 64-key tile with COMPILE-TIME buffer index CUR
#define ATTN_TILE(CUR, t_)                                                      \
  {                                                                             \
    const int k0 = (t_) * 64;                                                   \
    __syncthreads();                  /* staged tile t_ visible */              \
    if ((t_) + 1 < T) STAGE(CUR ^ 1, (t_) + 1);  /* in flight during compute */ \
    f32x4 st[4] = {};                                                           \
    __builtin_amdgcn_s_setprio(1);                                              \
    _Pragma("unroll")                                                           \
    for (int keyg = 0; keyg < 4; ++keyg) {                                      \
      _Pragma("unroll")                                                         \
      for (int kk = 0; kk < 2; ++kk) {                                          \
        const int r = keyg * 16 + l16;                                          \
        const int cp = (kk * 64 + quad * 16) ^ ((r & 7) << 4);                  \
        bf16x8 kf = *(const bf16x8*)&KV[CUR][r][cp >> 1];                       \
        st[keyg] = __builtin_amdgcn_mfma_f32_16x16x32_bf16(kf, qf[kk], st[keyg], 0, 0, 0); \
      }                                                                         \
    }                                                                           \
    __builtin_amdgcn_s_setprio(0);                                              \
    bf16x8 vf[4][2];                                                            \
    _Pragma("unroll")                                                           \
    for (int dg = 0; dg < 4; ++dg) {                                            \
      _Pragma("unroll")                                                         \
      for (int half = 0; half < 2; ++half) {                                    \
        const int row = 64 + dg * 16 + l16;                                     \
        const int cp = (half * 64 + quad * 16) ^ ((row & 7) << 4);              \
        vf[dg][half] = *(const bf16x8*)&KV[CUR][row][cp >> 1];                  \
      }                                                                         \
    }                                                                           \
    if ((t_) == T - 1) { /* causal mask: diagonal tile only */                  \
      _Pragma("unroll")                                                         \
      for (int keyg = 0; keyg < 4; ++keyg) {                                    \
        _Pragma("unroll")                                                       \
        for (int r = 0; r < 4; ++r) {                                           \
          const int key = k0 + keyg * 16 + quad * 4 + r;                        \
          if (key > q0 + wave * 16 + l16) st[keyg][r] = -INFINITY;              \
        }                                                                       \
      }                                                                         \
    }                                                                           \
    _Pragma("unroll")                                                           \
    for (int keyg = 0; keyg < 4; ++keyg) {                                      \
      float p0 = fexp2(st[keyg][0]);                                            \
      float p1 = fexp2(st[keyg][1]);                                            \
      float p2 = fexp2(st[keyg][2]);                                            \
      float p3 = fexp2(st[keyg][3]);                                            \
      uint2 pk;  /* truncate-to-bf16 pack via v_perm */                         \
      pk.x = __builtin_amdgcn_perm(fb(p1), fb(p0), 0x07060302u);                \
      pk.y = __builtin_amdgcn_perm(fb(p3), fb(p2), 0x07060302u);                \
      *(uint2*)&Pt[wave][l16][(keyg * 16 + quad * 4) ^ psw] = pk;               \
    }                                                                           \
    bf16x8 pb[2];                                                               \
    _Pragma("unroll")                                                           \
    for (int half = 0; half < 2; ++half)                                        \
      pb[half] = *(const bf16x8*)&Pt[wave][l16][(half * 32 + quad * 8) ^ psw];  \
    __builtin_amdgcn_s_setprio(1);                                              \
    _Pragma("unroll")                                                           \
    for (int dg = 0; dg < 4; ++dg) {                                            \
      o[dg] = __builtin_amdgcn_mfma_f32_16x16x32_bf16(vf[dg][0], pb[0], o[dg], 0, 0, 0); \
      o[dg] = __builtin_amdgcn_mfma_f32_16x16x32_bf16(vf[dg][1], pb[1], o[dg], 0, 0, 0); \
    }                                                                           \
    o[4] = __builtin_amdgcn_mfma_f32_16x16x32_bf16(ones, pb[0], o[4], 0, 0, 0); \
    o[4] = __builtin_amdgcn_mfma_f32_16x16x32_bf16(ones, pb[1], o[4], 0, 0, 0); \
    __builtin_amdgcn_s_setprio(0);                                              \
  }

  STAGE(0, 0);
  for (int t = 0; t < T; t += 2) {
    ATTN_TILE(0, t);
    if (t + 1 < T) ATTN_TILE(1, t + 1);
  }
#undef ATTN_TILE
#undef STAGE

  // ---- epilogue: no merge — wave owns its 16 queries entirely ----
  const float inv = 1.f / o[4][0];
  const size_t base = (size_t)(b * 2048 + q0 + wave * 16 + l16) * 1024 + h * 64;
#pragma unroll
  for (int dg = 0; dg < 4; ++dg) {
    ushort4 us;
    us.x = f2bf(o[dg][0] * inv); us.y = f2bf(o[dg][1] * inv);
    us.z = f2bf(o[dg][2] * inv); us.w = f2bf(o[dg][3] * inv);
    *(ushort4*)&ctx[base + dg * 16 + quad * 4] = us;
  }
}

// ---------------- launch ----------------
extern "C" void kernel_launch(void* const* d_in, const int* in_sizes, int n_in,
                              void* d_out, int out_size, void* d_ws, size_t ws_size,
                              hipStream_t stream) {
  const float* x  = (const float*)d_in[0];
  const float* Wq = (const float*)d_in[1];
  const float* Wk = (const float*)d_in[2];
  const float* Wv = (const float*)d_in[3];
  const float* Wo = (const float*)d_in[4];
  const float* bo = (const float*)d_in[5];
  float* out = (float*)d_out;

  // workspace layout (48 MB total)
  char* ws = (char*)d_ws;
  unsigned short* Xb    = (unsigned short*)(ws);                          //  8 MB [4096][1024]
  unsigned short* Wqkvt = (unsigned short*)(ws + (size_t)8  * 1048576);   //  6 MB [3072][1024]
  unsigned short* Wot   = (unsigned short*)(ws + (size_t)14 * 1048576);   //  2 MB [1024][1024]
  unsigned short* Qhb   = (unsigned short*)(ws + (size_t)16 * 1048576);   //  8 MB [32][2048][64]
  unsigned short* Khb   = (unsigned short*)(ws + (size_t)24 * 1048576);   //  8 MB [32][2048][64]
  unsigned short* Vtb   = (unsigned short*)(ws + (size_t)32 * 1048576);   //  8 MB [32][64][64][32]
  unsigned short* CT    = (unsigned short*)(ws + (size_t)40 * 1048576);   //  8 MB [4096][1024]

  prep_kernel<<<dim3(32, 32, 5), 256, 0, stream>>>(x, Wq, Wk, Wv, Wo, Xb, Wqkvt, Wot);
  gemm_qkv<<<768, 256, 0, stream>>>(Xb, Wqkvt, Qhb, Khb, Vtb, 1024);
  attn_kernel<<<1024, 256, 0, stream>>>(Qhb, Khb, Vtb, CT);
  gemm_out<<<512, 256, 0, stream>>>(CT, Wot, out, bo, 1024, 1024);
}